// Round 8
// baseline (199.203 us; speedup 1.0000x reference)
//
#include <hip/hip_runtime.h>
#include <hip/hip_bf16.h>
#include <math.h>

#define B_ 2
#define N_ 4096
#define C_ 256
#define H_ 8
#define K_ 32
#define NP_ (B_*N_)
#define CAPW 256

typedef __attribute__((ext_vector_type(8))) short bf16x8;
typedef __attribute__((ext_vector_type(4))) float f32x4;

__device__ __forceinline__ float bf2f(unsigned short v){
    union { unsigned int u; float f; } x; x.u = ((unsigned int)v) << 16; return x.f;
}
__device__ __forceinline__ unsigned short f2bf(float f){
    union { float f; unsigned int u; } x; x.f = f;
    return (unsigned short)((x.u + 0x7FFFu + ((x.u >> 16) & 1u)) >> 16);
}
__device__ __forceinline__ unsigned int mono(float f){
    union { float f; unsigned int u; } x; x.f = f;
    return x.u ^ (0x80000000u | (unsigned int)((int)x.u >> 31));
}

// ---------------- batched weight fp32 -> bf16 into contiguous Wbase ----------------
__global__ __launch_bounds__(256) void k_cvt_all(
    const float* __restrict__ s0, const float* __restrict__ s1,
    const float* __restrict__ s2, const float* __restrict__ s3,
    const float* __restrict__ s4, const float* __restrict__ s5,
    const float* __restrict__ s6, unsigned short* __restrict__ dst)
{
    int i = blockIdx.x*256 + threadIdx.x;   // 3328*256 = 851968 exactly
    float v;
    if (i < 327680){
        int seg = i >> 16, off = i & 65535;
        const float* s = (seg==0)?s0:(seg==1)?s1:(seg==2)?s2:(seg==3)?s3:s4;
        v = s[off];
    } else if (i < 720896){
        v = s5[i - 327680];
    } else {
        v = s6[i - 720896];
    }
    dst[i] = f2bf(v);
}

// ---------------- pack xyzB -> (-2x,-2y,-2z,|p|^2) float4 ----------------
__global__ __launch_bounds__(256) void k_prep(const float* __restrict__ xyzB,
                                              f32x4* __restrict__ PB){
    int i = blockIdx.x*256 + threadIdx.x;
    if (i < NP_){
        float x = xyzB[i*3], y = xyzB[i*3+1], z = xyzB[i*3+2];
        f32x4 o;
        o[0] = -2.f*x; o[1] = -2.f*y; o[2] = -2.f*z;
        o[3] = x*x + y*y + z*z;
        PB[i] = o;
    }
}

// ---------------- Morton-bucket ordering of query points (locality heuristic) -----
// 1 block per batch. 10-bit code (x:4,y:3,z:3 interleaved), 1024 buckets,
// LDS histogram + scan + scatter -> order[batch*4096 + pos] = (batch<<12)|n.
__global__ __launch_bounds__(256) void k_morton(const float* __restrict__ xyzA,
                                                int* __restrict__ order){
    __shared__ unsigned int hist[1024];
    __shared__ unsigned int wsum[4];
    const int b = blockIdx.x;
    const int tid = threadIdx.x;
    const int wv = tid >> 6, lane = tid & 63;
    for (int i = tid; i < 1024; i += 256) hist[i] = 0u;
    __syncthreads();
    unsigned int code[16];
    #pragma unroll
    for (int i = 0; i < 16; i++){
        const int n = tid + i*256;
        const float* pp = xyzA + (size_t)((b<<12) + n)*3;
        int qx = (int)fminf(fmaxf((pp[0] + 5.f)*1.6f, 0.f), 15.f);
        int qy = (int)fminf(fmaxf((pp[1] + 5.f)*0.8f, 0.f), 7.f);
        int qz = (int)fminf(fmaxf((pp[2] + 5.f)*0.8f, 0.f), 7.f);
        unsigned int c = (unsigned int)((qx & 1) | ((qz & 1) << 1) | ((qy & 1) << 2)
                       | (((qx >> 1) & 1) << 3) | (((qz >> 1) & 1) << 4) | (((qy >> 1) & 1) << 5)
                       | (((qx >> 2) & 1) << 6) | (((qz >> 2) & 1) << 7) | (((qy >> 2) & 1) << 8)
                       | (((qx >> 3) & 1) << 9));
        code[i] = c;
        atomicAdd(&hist[c], 1u);
    }
    __syncthreads();
    // exclusive scan of 1024 bins (4 bins/thread)
    unsigned int loc[4], t4 = 0;
    #pragma unroll
    for (int j = 0; j < 4; j++){ loc[j] = hist[tid*4 + j]; t4 += loc[j]; }
    unsigned int sc = t4;
    #pragma unroll
    for (int off = 1; off < 64; off <<= 1){
        unsigned int o = __shfl_up(sc, off, 64);
        if (lane >= off) sc += o;
    }
    if (lane == 63) wsum[wv] = sc;
    __syncthreads();
    unsigned int wb = 0;
    #pragma unroll
    for (int j = 0; j < 4; j++) if (j < wv) wb += wsum[j];
    unsigned int base = wb + sc - t4;
    #pragma unroll
    for (int j = 0; j < 4; j++){ hist[tid*4 + j] = base; base += loc[j]; }
    __syncthreads();
    #pragma unroll
    for (int i = 0; i < 16; i++){
        const int n = tid + i*256;
        unsigned int pos = atomicAdd(&hist[code[i]], 1u);
        order[(b<<12) + pos] = (b<<12) | n;
    }
}

// ---------------- fused LN(featA) + transpose -> F cols 0..255 (bf16) --------------
__global__ __launch_bounds__(256) void k_lnt(const float* __restrict__ fa,
        const float* __restrict__ lnw, const float* __restrict__ lnb,
        unsigned short* __restrict__ F){
    __shared__ float tile[32][257];
    __shared__ float ps[8][32], pq[8][32];
    __shared__ float st[2][32];
    const int t = threadIdx.x;
    const int nx = t & 31, cy = t >> 5;
    const int pbase = blockIdx.x * 32;
    const int b = pbase >> 12, n0 = pbase & 4095;
    const float* sp = fa + (size_t)b*C_*N_ + n0;
    #pragma unroll 4
    for (int it = 0; it < 32; it++){
        int c = cy + it*8;
        tile[nx][c] = sp[(size_t)c*N_ + nx];
    }
    __syncthreads();
    {
        float s = 0.f, q = 0.f;
        #pragma unroll 8
        for (int i = 0; i < 32; i++){
            int cc = cy*32 + ((i + cy) & 31);
            float x = tile[nx][cc];
            s += x; q = fmaf(x, x, q);
        }
        ps[cy][nx] = s; pq[cy][nx] = q;
    }
    __syncthreads();
    if (t < 32){
        float S = 0.f, Q = 0.f;
        #pragma unroll
        for (int j = 0; j < 8; j++){ S += ps[j][t]; Q += pq[j][t]; }
        float m = S*(1.f/256.f);
        float v = Q*(1.f/256.f) - m*m;
        st[0][t] = m; st[1][t] = rsqrtf(v + 1e-5f);
    }
    __syncthreads();
    const int p = pbase + nx;
    const float m = st[0][nx], r = st[1][nx];
    #pragma unroll
    for (int j = 0; j < 4; j++){
        bf16x8 ob;
        #pragma unroll
        for (int e = 0; e < 8; e++){
            int c = cy*32 + j*8 + e;
            ob[e] = (short)f2bf((tile[nx][c]-m)*r*lnw[c] + lnb[c]);
        }
        *(bf16x8*)(F + (size_t)p*768 + cy*32 + j*8) = ob;
    }
}

// ---------------- transpose featB (B,C,N)->(B,N,C) bf16 ----------------
__global__ __launch_bounds__(256) void k_transpose(const float* __restrict__ src,
                            unsigned short* __restrict__ dst){
    __shared__ float tile[64][65];
    const int b = blockIdx.z;
    const int n0 = blockIdx.x*64, c0 = blockIdx.y*64;
    const int tx = threadIdx.x & 63, ty = threadIdx.x >> 6;
    const float* sp = src + (size_t)b*C_*N_;
    #pragma unroll
    for (int i = 0; i < 16; i++){
        int cr = ty + i*4;
        tile[cr][tx] = sp[(size_t)(c0+cr)*N_ + n0 + tx];
    }
    __syncthreads();
    const int c = c0 + tx;
    #pragma unroll
    for (int i = 0; i < 16; i++){
        int nr = ty + i*4;
        int p = (b<<12) + n0 + nr;
        dst[(size_t)p*256 + c] = f2bf(tile[tx][nr]);
    }
}

// ---------------- KNN: storage-free two-pass, one query per wave ----------------
__global__ __launch_bounds__(256) void k_knn(const float* __restrict__ xyzA,
        const f32x4* __restrict__ PB, int* __restrict__ knn){
    const int wv = threadIdx.x >> 6, lane = threadIdx.x & 63;
    const int p = blockIdx.x*4 + wv;
    const int b = p >> 12;
    const f32x4* pb = PB + ((size_t)b << 12);
    const float ax = xyzA[(size_t)p*3], ay = xyzA[(size_t)p*3+1], az = xyzA[(size_t)p*3+2];

    unsigned long long mn = ~0ull;
    #pragma unroll 8
    for (int i = 0; i < 64; i++){
        const int m = i*64 + lane;
        f32x4 c = pb[m];
        float d = fmaf(ax, c[0], fmaf(ay, c[1], fmaf(az, c[2], c[3])));
        unsigned long long key = (((unsigned long long)mono(d)) << 12) | (unsigned int)m;
        mn = key < mn ? key : mn;
    }
    unsigned int rk = 0;
    for (int j = 0; j < 64; j++){
        unsigned long long o = __shfl(mn, j, 64);
        rk += (o < mn) ? 1u : 0u;
    }
    unsigned long long sel = (rk == 31u) ? mn : ~0ull;
    #pragma unroll
    for (int off = 32; off; off >>= 1){
        unsigned long long o = __shfl_xor(sel, off, 64);
        sel = o < sel ? o : sel;
    }
    const unsigned long long v = sel;
    const unsigned int vhi = (unsigned int)(v >> 12);
    const unsigned int vlo = (unsigned int)(v & 0xFFFull);

    __shared__ unsigned long long cand[4][CAPW];
    __shared__ unsigned int cnt[4];
    if (lane == 0) cnt[wv] = 0u;
    #pragma unroll 8
    for (int i = 0; i < 64; i++){
        const int m = i*64 + lane;
        f32x4 c = pb[m];
        float d = fmaf(ax, c[0], fmaf(ay, c[1], fmaf(az, c[2], c[3])));
        unsigned int u = mono(d);
        if (u < vhi || (u == vhi && (unsigned int)m <= vlo)){
            unsigned int slot = atomicAdd(&cnt[wv], 1u);
            if (slot < CAPW)
                cand[wv][slot] = (((unsigned long long)u) << 12) | (unsigned int)m;
        }
    }
    const unsigned int C = cnt[wv];
    if (C <= CAPW){
        for (unsigned int i = lane; i < C; i += 64){
            unsigned long long mk = cand[wv][i];
            unsigned int rank = 0;
            for (unsigned int j = 0; j < C; j++) rank += (cand[wv][j] < mk) ? 1u : 0u;
            if (rank < K_) knn[(size_t)p*K_ + rank] = (int)(mk & 0xFFFull);
        }
    } else {
        unsigned long long last = 0ull;
        for (int it = 0; it < K_; it++){
            unsigned long long cm = ~0ull;
            #pragma unroll 4
            for (int i = 0; i < 64; i++){
                const int m = i*64 + lane;
                f32x4 c = pb[m];
                float d = fmaf(ax, c[0], fmaf(ay, c[1], fmaf(az, c[2], c[3])));
                unsigned long long key = (((unsigned long long)mono(d)) << 12) | (unsigned int)m;
                if (key > last && key < cm) cm = key;
            }
            #pragma unroll
            for (int off = 32; off; off >>= 1){
                unsigned long long o = __shfl_xor(cm, off, 64);
                cm = o < cm ? o : cm;
            }
            if (lane == 0) knn[(size_t)p*K_ + it] = (int)(cm & 0xFFFull);
            last = cm;
        }
    }
}

// ---------------- MFMA GEMM with K-step register prefetch pipeline --------------
template<int MODE>
__global__ __launch_bounds__(256) void k_gemm(
    const unsigned short* __restrict__ X, int ldx,
    const unsigned short* __restrict__ W, int Kin,
    const float* __restrict__ e0, const float* __restrict__ e1, const float* __restrict__ e2,
    unsigned short* __restrict__ Y, int ldy,
    const float* __restrict__ resid, float* __restrict__ out)
{
    const int wid = threadIdx.x >> 6, lane = threadIdx.x & 63;
    const int lr = lane & 15, lg = lane >> 4;
    const int mw = blockIdx.x * 128 + wid * 32;
    const int cn = blockIdx.y * 64;
    f32x4 acc[2][4] = {};
    const unsigned short* xr0 = X + (size_t)(mw + lr) * ldx + lg*8;
    const unsigned short* xr1 = xr0 + (size_t)16 * ldx;
    const unsigned short* wr0 = W + (size_t)(cn + lr) * Kin + lg*8;
    bf16x8 a0 = *(const bf16x8*)(xr0);
    bf16x8 a1 = *(const bf16x8*)(xr1);
    bf16x8 b0 = *(const bf16x8*)(wr0);
    bf16x8 b1 = *(const bf16x8*)(wr0 + (size_t)16*Kin);
    bf16x8 b2 = *(const bf16x8*)(wr0 + (size_t)32*Kin);
    bf16x8 b3 = *(const bf16x8*)(wr0 + (size_t)48*Kin);
    for (int k0 = 0; k0 < Kin; k0 += 32){
        bf16x8 na0 = a0, na1 = a1, nb0 = b0, nb1 = b1, nb2 = b2, nb3 = b3;
        const int k = k0 + 32;
        if (k < Kin){
            na0 = *(const bf16x8*)(xr0 + k);
            na1 = *(const bf16x8*)(xr1 + k);
            nb0 = *(const bf16x8*)(wr0 + k);
            nb1 = *(const bf16x8*)(wr0 + (size_t)16*Kin + k);
            nb2 = *(const bf16x8*)(wr0 + (size_t)32*Kin + k);
            nb3 = *(const bf16x8*)(wr0 + (size_t)48*Kin + k);
        }
        acc[0][0] = __builtin_amdgcn_mfma_f32_16x16x32_bf16(a0, b0, acc[0][0], 0, 0, 0);
        acc[1][0] = __builtin_amdgcn_mfma_f32_16x16x32_bf16(a1, b0, acc[1][0], 0, 0, 0);
        acc[0][1] = __builtin_amdgcn_mfma_f32_16x16x32_bf16(a0, b1, acc[0][1], 0, 0, 0);
        acc[1][1] = __builtin_amdgcn_mfma_f32_16x16x32_bf16(a1, b1, acc[1][1], 0, 0, 0);
        acc[0][2] = __builtin_amdgcn_mfma_f32_16x16x32_bf16(a0, b2, acc[0][2], 0, 0, 0);
        acc[1][2] = __builtin_amdgcn_mfma_f32_16x16x32_bf16(a1, b2, acc[1][2], 0, 0, 0);
        acc[0][3] = __builtin_amdgcn_mfma_f32_16x16x32_bf16(a0, b3, acc[0][3], 0, 0, 0);
        acc[1][3] = __builtin_amdgcn_mfma_f32_16x16x32_bf16(a1, b3, acc[1][3], 0, 0, 0);
        a0 = na0; a1 = na1; b0 = nb0; b1 = nb1; b2 = nb2; b3 = nb3;
    }
    #pragma unroll
    for (int mi = 0; mi < 2; mi++){
        const int pbase = mw + mi*16 + lg*4;
        #pragma unroll
        for (int ni = 0; ni < 4; ni++){
            const int o = cn + ni*16 + lr;
            if (MODE == 0){
                const float* bp = (o < 256) ? e0 : ((o < 512) ? e1 : e2);
                float bias = bp[o & 255];
                #pragma unroll
                for (int r = 0; r < 4; r++)
                    Y[(size_t)(pbase + r)*ldy + o] = f2bf(acc[mi][ni][r] + bias);
            } else if (MODE == 1){
                float sc = e0[o] * 0.9999950000374997f;   // rsqrt(1+1e-5)*bn_g
                float sh = e1[o];
                #pragma unroll
                for (int r = 0; r < 4; r++){
                    float vv = fmaf(acc[mi][ni][r], sc, sh);
                    Y[(size_t)(pbase + r)*ldy + o] = f2bf(fmaxf(vv, 0.f));
                }
            } else {
                float bias = e0[o];
                const int b = pbase >> 12, nn = pbase & 4095;
                const size_t adr = ((size_t)b*C_ + o)*N_ + nn;
                f32x4 rv = *(const f32x4*)(resid + adr);
                f32x4 ov;
                #pragma unroll
                for (int r = 0; r < 4; r++) ov[r] = acc[mi][ni][r] + bias + rv[r];
                *(f32x4*)(out + adr) = ov;
            }
        }
    }
}

// ---------------- dual-path neighbor attention: 2 waves per point (head halves) ----
// Morton-ordered work assignment: XCD (bid&7) -> {batch, quarter of sorted order}.
__global__ __launch_bounds__(256) void k_attn(
    const unsigned short* __restrict__ QQ, const unsigned short* __restrict__ KVD,
    const int* __restrict__ KNN, const int* __restrict__ order,
    const float* __restrict__ lnsw, const float* __restrict__ lnsb,
    const float* __restrict__ lndw, const float* __restrict__ lndb,
    unsigned short* __restrict__ F)
{
    __shared__ float q_l[2][2][2][128];       // [ps][wh][sim/dis][dim]
    __shared__ float w_l[2][2][2][4][33];     // [ps][wh][path][h_local][k] (pad 33)
    __shared__ int   idx_l[2][2][32];         // per-wave copy -> no stage barrier
    __shared__ float part_l[2][2][4];

    const int tid = threadIdx.x;
    const int wid = tid >> 6, lane = tid & 63;
    const int ps = wid >> 1, wh = wid & 1;
    const int bid = blockIdx.x;                 // 4096 blocks
    const int xcd = bid & 7, ib = bid >> 3;
    const int batch = xcd & 1, quarter = xcd >> 1;
    const int jj = quarter*1024 + ib*2 + ps;
    const int p = order[(batch << 12) + jj];
    const int b = batch;

    {
        const unsigned short* qrow = QQ + (size_t)p*512 + wh*128 + lane*2;
        unsigned int us = *(const unsigned int*)qrow;
        unsigned int ud = *(const unsigned int*)(qrow + 256);
        q_l[ps][wh][0][lane*2]   = bf2f((unsigned short)(us & 0xffff));
        q_l[ps][wh][0][lane*2+1] = bf2f((unsigned short)(us >> 16));
        q_l[ps][wh][1][lane*2]   = bf2f((unsigned short)(ud & 0xffff));
        q_l[ps][wh][1][lane*2+1] = bf2f((unsigned short)(ud >> 16));
        if (lane < 32) idx_l[ps][wh][lane] = KNN[(size_t)p*K_ + lane];
    }
    // all LDS below (q_l, w_l, idx_l) is wave-local: no barrier needed until LN combine

    const int hh = lane >> 5, kk = lane & 31;
    {
        const int nbr = idx_l[ps][wh][kk];
        const unsigned short* rowb = KVD + (size_t)((b<<12) + nbr)*768;
        bf16x8 kx[2][4], dx[2][4];
        #pragma unroll
        for (int j = 0; j < 2; j++){
            const int h = wh*4 + j*2 + hh;
            const bf16x8* kr = (const bf16x8*)(rowb + h*32);
            const bf16x8* dr = (const bf16x8*)(rowb + 512 + h*32);
            #pragma unroll
            for (int c = 0; c < 4; c++){ kx[j][c] = kr[c]; dx[j][c] = dr[c]; }
        }
        #pragma unroll
        for (int j = 0; j < 2; j++){
            const int hl = j*2 + hh;
            const float* qs = &q_l[ps][wh][0][hl*32];
            const float* qd = &q_l[ps][wh][1][hl*32];
            float s = 0.f, dd = 0.f;
            #pragma unroll
            for (int c = 0; c < 4; c++){
                #pragma unroll
                for (int e = 0; e < 8; e++){
                    const int d = c*8 + e;
                    s = fmaf(qs[d], bf2f((unsigned short)kx[j][c][e]), s);
                    float df = qd[d] - bf2f((unsigned short)dx[j][c][e]);
                    dd = fmaf(df, df, dd);
                }
            }
            float sim = s * 0.17677669529663687f;   // 1/sqrt(32)
            float dist = sqrtf(dd);
            float m1 = sim, m2 = dist;
            #pragma unroll
            for (int off = 1; off < 32; off <<= 1){
                m1 = fmaxf(m1, __shfl_xor(m1, off, 64));
                m2 = fmaxf(m2, __shfl_xor(m2, off, 64));
            }
            float e1v = __expf(sim - m1);
            float e2v = __expf(dist - m2);
            float s1 = e1v, s2 = e2v;
            #pragma unroll
            for (int off = 1; off < 32; off <<= 1){
                s1 += __shfl_xor(s1, off, 64);
                s2 += __shfl_xor(s2, off, 64);
            }
            w_l[ps][wh][0][hl][kk] = e1v / s1;
            w_l[ps][wh][1][hl][kk] = e2v / s2;
        }
    }

    const int tq = lane >> 4, c = lane & 15;
    float cs[8] = {0,0,0,0,0,0,0,0}, cd[8] = {0,0,0,0,0,0,0,0};
    {
        const unsigned short* vbase = KVD + 256 + wh*128 + c*8;
        const int hl = c >> 2;
        int t = tq;
        int nbr = idx_l[ps][wh][t];
        bf16x8 cur = *(const bf16x8*)(vbase + (size_t)((b<<12) + nbr)*768);
        #pragma unroll
        for (int i = 0; i < 8; i++){
            bf16x8 nxt = cur;
            if (i < 7){
                int nn = idx_l[ps][wh][t + 4];
                nxt = *(const bf16x8*)(vbase + (size_t)((b<<12) + nn)*768);
            }
            const float wsv = w_l[ps][wh][0][hl][t];
            const float wdv = w_l[ps][wh][1][hl][t];
            #pragma unroll
            for (int e = 0; e < 8; e++){
                float vf = bf2f((unsigned short)cur[e]);
                cs[e] = fmaf(wsv, vf, cs[e]);
                cd[e] = fmaf(wdv, vf, cd[e]);
            }
            cur = nxt; t += 4;
        }
    }
    #pragma unroll
    for (int e = 0; e < 8; e++){
        cs[e] += __shfl_xor(cs[e], 16, 64); cs[e] += __shfl_xor(cs[e], 32, 64);
        cd[e] += __shfl_xor(cd[e], 16, 64); cd[e] += __shfl_xor(cd[e], 32, 64);
    }
    float s1 = 0.f, q1 = 0.f, s2 = 0.f, q2 = 0.f;
    #pragma unroll
    for (int e = 0; e < 8; e++){
        s1 += cs[e]; q1 = fmaf(cs[e], cs[e], q1);
        s2 += cd[e]; q2 = fmaf(cd[e], cd[e], q2);
    }
    #pragma unroll
    for (int off = 1; off < 16; off <<= 1){
        s1 += __shfl_xor(s1, off, 64); q1 += __shfl_xor(q1, off, 64);
        s2 += __shfl_xor(s2, off, 64); q2 += __shfl_xor(q2, off, 64);
    }
    if (lane == 0){
        part_l[ps][wh][0] = s1; part_l[ps][wh][1] = q1;
        part_l[ps][wh][2] = s2; part_l[ps][wh][3] = q2;
    }
    __syncthreads();
    const float S1 = s1 + part_l[ps][wh^1][0];
    const float Q1 = q1 + part_l[ps][wh^1][1];
    const float S2 = s2 + part_l[ps][wh^1][2];
    const float Q2 = q2 + part_l[ps][wh^1][3];
    const float m1 = S1*(1.f/256.f), m2 = S2*(1.f/256.f);
    const float r1 = rsqrtf(Q1*(1.f/256.f) - m1*m1 + 1e-5f);
    const float r2 = rsqrtf(Q2*(1.f/256.f) - m2*m2 + 1e-5f);

    if (tq == 0){
        bf16x8 ob;
        #pragma unroll
        for (int e = 0; e < 8; e++){
            const int cg = wh*128 + c*8 + e;
            ob[e] = (short)f2bf((cs[e]-m1)*r1*lnsw[cg] + lnsb[cg]);
        }
        *(bf16x8*)(F + (size_t)p*768 + 256 + wh*128 + c*8) = ob;
    } else if (tq == 1){
        bf16x8 ob;
        #pragma unroll
        for (int e = 0; e < 8; e++){
            const int cg = wh*128 + c*8 + e;
            ob[e] = (short)f2bf((cd[e]-m2)*r2*lndw[cg] + lndb[cg]);
        }
        *(bf16x8*)(F + (size_t)p*768 + 512 + wh*128 + c*8) = ob;
    }
}

extern "C" void kernel_launch(void* const* d_in, const int* in_sizes, int n_in,
                              void* d_out, int out_size, void* d_ws, size_t ws_size,
                              hipStream_t stream)
{
    const float* xyzA   = (const float*)d_in[0];
    const float* xyzB   = (const float*)d_in[1];
    const float* featA  = (const float*)d_in[2];
    const float* featB  = (const float*)d_in[3];
    const float* ln_in_w= (const float*)d_in[4];
    const float* ln_in_b= (const float*)d_in[5];
    const float* wq  = (const float*)d_in[6];
    const float* bq  = (const float*)d_in[7];
    const float* wk  = (const float*)d_in[8];
    const float* bk  = (const float*)d_in[9];
    const float* wv  = (const float*)d_in[10];
    const float* bv  = (const float*)d_in[11];
    const float* wqd = (const float*)d_in[12];
    const float* bqd = (const float*)d_in[13];
    const float* wkd = (const float*)d_in[14];
    const float* bkd = (const float*)d_in[15];
    const float* lnsw = (const float*)d_in[16];
    const float* lnsb = (const float*)d_in[17];
    const float* lndw = (const float*)d_in[18];
    const float* lndb = (const float*)d_in[19];
    const float* fw1 = (const float*)d_in[20];
    const float* bng = (const float*)d_in[21];
    const float* bnb = (const float*)d_in[22];
    const float* fw2 = (const float*)d_in[23];
    const float* fb2 = (const float*)d_in[24];
    float* out = (float*)d_out;
    char* ws = (char*)d_ws;

    unsigned short* F    = (unsigned short*)(ws + 0);          // 8192*768 bf16
    unsigned short* XBT  = (unsigned short*)(ws + 12582912);   // 8192*256
    unsigned short* QQ   = (unsigned short*)(ws + 16777216);   // 8192*512
    unsigned short* KVD  = (unsigned short*)(ws + 25165824);   // 8192*768
    unsigned short* Y1   = (unsigned short*)(ws + 37748736);   // 8192*512 (GEMM) ; PB (knn, earlier)
    f32x4*          PB   = (f32x4*)(ws + 37748736);            // 8192*16B, dead before fus1
    int*            KNNi = (int*)(ws + 46137344);              // 8192*32
    int*            ORD  = (int*)(ws + 47185920);              // 8192*4 = 32KB
    unsigned short* Wb   = (unsigned short*)(ws + 47251456);   // 851968 bf16
    unsigned short* WQcat = Wb;                // 512x256
    unsigned short* WKVD  = Wb + 131072;       // 768x256
    unsigned short* W1b   = Wb + 327680;       // 512x768
    unsigned short* W2b   = Wb + 720896;       // 256x512

    k_cvt_all<<<3328, 256, 0, stream>>>(wq, wqd, wk, wv, wkd, fw1, fw2, Wb);
    k_prep<<<32, 256, 0, stream>>>(xyzB, PB);
    k_morton<<<2, 256, 0, stream>>>(xyzA, ORD);

    k_lnt<<<256, 256, 0, stream>>>(featA, ln_in_w, ln_in_b, F);
    k_transpose<<<dim3(64,4,2), 256, 0, stream>>>(featB, XBT);
    k_knn<<<2048, 256, 0, stream>>>(xyzA, PB, KNNi);

    k_gemm<0><<<dim3(64,8), 256, 0, stream>>>(F,   768, WQcat, 256, bq, bqd, nullptr, QQ, 512, nullptr, nullptr);
    k_gemm<0><<<dim3(64,12), 256, 0, stream>>>(XBT, 256, WKVD, 256, bk, bv, bkd, KVD, 768, nullptr, nullptr);

    k_attn<<<4096, 256, 0, stream>>>(QQ, KVD, KNNi, ORD, lnsw, lnsb, lndw, lndb, F);

    k_gemm<1><<<dim3(64,8), 256, 0, stream>>>(F,  768, W1b, 768, bng, bnb, nullptr, Y1, 512, nullptr, nullptr);
    k_gemm<2><<<dim3(64,4), 256, 0, stream>>>(Y1, 512, W2b, 512, fb2, nullptr, nullptr, nullptr, 0, featA, out);
}

// Round 9
// 166.343 us; speedup vs baseline: 1.1975x; 1.1975x over previous
//
#include <hip/hip_runtime.h>
#include <hip/hip_bf16.h>
#include <math.h>

#define B_ 2
#define N_ 4096
#define C_ 256
#define H_ 8
#define K_ 32
#define NP_ (B_*N_)
#define CAPW 256

typedef __attribute__((ext_vector_type(8))) short bf16x8;
typedef __attribute__((ext_vector_type(4))) float f32x4;

__device__ __forceinline__ float bf2f(unsigned short v){
    union { unsigned int u; float f; } x; x.u = ((unsigned int)v) << 16; return x.f;
}
__device__ __forceinline__ unsigned short f2bf(float f){
    union { float f; unsigned int u; } x; x.f = f;
    return (unsigned short)((x.u + 0x7FFFu + ((x.u >> 16) & 1u)) >> 16);
}
__device__ __forceinline__ unsigned int mono(float f){
    union { float f; unsigned int u; } x; x.f = f;
    return x.u ^ (0x80000000u | (unsigned int)((int)x.u >> 31));
}
__device__ __forceinline__ void gload_lds16(const unsigned short* g, unsigned short* l){
    __builtin_amdgcn_global_load_lds(
        (const __attribute__((address_space(1))) unsigned int*)g,
        (__attribute__((address_space(3))) unsigned int*)l, 16, 0, 0);
}

// ---------------- batched weight fp32 -> bf16 into contiguous Wbase ----------------
__global__ __launch_bounds__(256) void k_cvt_all(
    const float* __restrict__ s0, const float* __restrict__ s1,
    const float* __restrict__ s2, const float* __restrict__ s3,
    const float* __restrict__ s4, const float* __restrict__ s5,
    const float* __restrict__ s6, unsigned short* __restrict__ dst)
{
    int i = blockIdx.x*256 + threadIdx.x;   // 3328*256 = 851968 exactly
    float v;
    if (i < 327680){
        int seg = i >> 16, off = i & 65535;
        const float* s = (seg==0)?s0:(seg==1)?s1:(seg==2)?s2:(seg==3)?s3:s4;
        v = s[off];
    } else if (i < 720896){
        v = s5[i - 327680];
    } else {
        v = s6[i - 720896];
    }
    dst[i] = f2bf(v);
}

// ---------------- pack xyzB -> (-2x,-2y,-2z,|p|^2) float4 ----------------
__global__ __launch_bounds__(256) void k_prep(const float* __restrict__ xyzB,
                                              f32x4* __restrict__ PB){
    int i = blockIdx.x*256 + threadIdx.x;
    if (i < NP_){
        float x = xyzB[i*3], y = xyzB[i*3+1], z = xyzB[i*3+2];
        f32x4 o;
        o[0] = -2.f*x; o[1] = -2.f*y; o[2] = -2.f*z;
        o[3] = x*x + y*y + z*z;
        PB[i] = o;
    }
}

// ---------------- Morton-bucket ordering of query points ----------------
__global__ __launch_bounds__(256) void k_morton(const float* __restrict__ xyzA,
                                                int* __restrict__ order){
    __shared__ unsigned int hist[1024];
    __shared__ unsigned int wsum[4];
    const int b = blockIdx.x;
    const int tid = threadIdx.x;
    const int wv = tid >> 6, lane = tid & 63;
    for (int i = tid; i < 1024; i += 256) hist[i] = 0u;
    __syncthreads();
    unsigned int code[16];
    #pragma unroll
    for (int i = 0; i < 16; i++){
        const int n = tid + i*256;
        const float* pp = xyzA + (size_t)((b<<12) + n)*3;
        int qx = (int)fminf(fmaxf((pp[0] + 5.f)*1.6f, 0.f), 15.f);
        int qy = (int)fminf(fmaxf((pp[1] + 5.f)*0.8f, 0.f), 7.f);
        int qz = (int)fminf(fmaxf((pp[2] + 5.f)*0.8f, 0.f), 7.f);
        unsigned int c = (unsigned int)((qx & 1) | ((qz & 1) << 1) | ((qy & 1) << 2)
                       | (((qx >> 1) & 1) << 3) | (((qz >> 1) & 1) << 4) | (((qy >> 1) & 1) << 5)
                       | (((qx >> 2) & 1) << 6) | (((qz >> 2) & 1) << 7) | (((qy >> 2) & 1) << 8)
                       | (((qx >> 3) & 1) << 9));
        code[i] = c;
        atomicAdd(&hist[c], 1u);
    }
    __syncthreads();
    unsigned int loc[4], t4 = 0;
    #pragma unroll
    for (int j = 0; j < 4; j++){ loc[j] = hist[tid*4 + j]; t4 += loc[j]; }
    unsigned int sc = t4;
    #pragma unroll
    for (int off = 1; off < 64; off <<= 1){
        unsigned int o = __shfl_up(sc, off, 64);
        if (lane >= off) sc += o;
    }
    if (lane == 63) wsum[wv] = sc;
    __syncthreads();
    unsigned int wb = 0;
    #pragma unroll
    for (int j = 0; j < 4; j++) if (j < wv) wb += wsum[j];
    unsigned int base = wb + sc - t4;
    #pragma unroll
    for (int j = 0; j < 4; j++){ hist[tid*4 + j] = base; base += loc[j]; }
    __syncthreads();
    #pragma unroll
    for (int i = 0; i < 16; i++){
        const int n = tid + i*256;
        unsigned int pos = atomicAdd(&hist[code[i]], 1u);
        order[(b<<12) + pos] = (b<<12) | n;
    }
}

// ---------------- fused LN(featA) + transpose -> F cols 0..255 (bf16) --------------
__global__ __launch_bounds__(256) void k_lnt(const float* __restrict__ fa,
        const float* __restrict__ lnw, const float* __restrict__ lnb,
        unsigned short* __restrict__ F){
    __shared__ float tile[32][257];
    __shared__ float ps[8][32], pq[8][32];
    __shared__ float st[2][32];
    const int t = threadIdx.x;
    const int nx = t & 31, cy = t >> 5;
    const int pbase = blockIdx.x * 32;
    const int b = pbase >> 12, n0 = pbase & 4095;
    const float* sp = fa + (size_t)b*C_*N_ + n0;
    #pragma unroll 4
    for (int it = 0; it < 32; it++){
        int c = cy + it*8;
        tile[nx][c] = sp[(size_t)c*N_ + nx];
    }
    __syncthreads();
    {
        float s = 0.f, q = 0.f;
        #pragma unroll 8
        for (int i = 0; i < 32; i++){
            int cc = cy*32 + ((i + cy) & 31);
            float x = tile[nx][cc];
            s += x; q = fmaf(x, x, q);
        }
        ps[cy][nx] = s; pq[cy][nx] = q;
    }
    __syncthreads();
    if (t < 32){
        float S = 0.f, Q = 0.f;
        #pragma unroll
        for (int j = 0; j < 8; j++){ S += ps[j][t]; Q += pq[j][t]; }
        float m = S*(1.f/256.f);
        float v = Q*(1.f/256.f) - m*m;
        st[0][t] = m; st[1][t] = rsqrtf(v + 1e-5f);
    }
    __syncthreads();
    const int p = pbase + nx;
    const float m = st[0][nx], r = st[1][nx];
    #pragma unroll
    for (int j = 0; j < 4; j++){
        bf16x8 ob;
        #pragma unroll
        for (int e = 0; e < 8; e++){
            int c = cy*32 + j*8 + e;
            ob[e] = (short)f2bf((tile[nx][c]-m)*r*lnw[c] + lnb[c]);
        }
        *(bf16x8*)(F + (size_t)p*768 + cy*32 + j*8) = ob;
    }
}

// ---------------- transpose featB (B,C,N)->(B,N,C) bf16 ----------------
__global__ __launch_bounds__(256) void k_transpose(const float* __restrict__ src,
                            unsigned short* __restrict__ dst){
    __shared__ float tile[64][65];
    const int b = blockIdx.z;
    const int n0 = blockIdx.x*64, c0 = blockIdx.y*64;
    const int tx = threadIdx.x & 63, ty = threadIdx.x >> 6;
    const float* sp = src + (size_t)b*C_*N_;
    #pragma unroll
    for (int i = 0; i < 16; i++){
        int cr = ty + i*4;
        tile[cr][tx] = sp[(size_t)(c0+cr)*N_ + n0 + tx];
    }
    __syncthreads();
    const int c = c0 + tx;
    #pragma unroll
    for (int i = 0; i < 16; i++){
        int nr = ty + i*4;
        int p = (b<<12) + n0 + nr;
        dst[(size_t)p*256 + c] = f2bf(tile[tx][nr]);
    }
}

// ---------------- KNN: storage-free two-pass, one query per wave ----------------
__global__ __launch_bounds__(256) void k_knn(const float* __restrict__ xyzA,
        const f32x4* __restrict__ PB, int* __restrict__ knn){
    const int wv = threadIdx.x >> 6, lane = threadIdx.x & 63;
    const int p = blockIdx.x*4 + wv;
    const int b = p >> 12;
    const f32x4* pb = PB + ((size_t)b << 12);
    const float ax = xyzA[(size_t)p*3], ay = xyzA[(size_t)p*3+1], az = xyzA[(size_t)p*3+2];

    unsigned long long mn = ~0ull;
    #pragma unroll 8
    for (int i = 0; i < 64; i++){
        const int m = i*64 + lane;
        f32x4 c = pb[m];
        float d = fmaf(ax, c[0], fmaf(ay, c[1], fmaf(az, c[2], c[3])));
        unsigned long long key = (((unsigned long long)mono(d)) << 12) | (unsigned int)m;
        mn = key < mn ? key : mn;
    }
    unsigned int rk = 0;
    for (int j = 0; j < 64; j++){
        unsigned long long o = __shfl(mn, j, 64);
        rk += (o < mn) ? 1u : 0u;
    }
    unsigned long long sel = (rk == 31u) ? mn : ~0ull;
    #pragma unroll
    for (int off = 32; off; off >>= 1){
        unsigned long long o = __shfl_xor(sel, off, 64);
        sel = o < sel ? o : sel;
    }
    const unsigned long long v = sel;
    const unsigned int vhi = (unsigned int)(v >> 12);
    const unsigned int vlo = (unsigned int)(v & 0xFFFull);

    __shared__ unsigned long long cand[4][CAPW];
    __shared__ unsigned int cnt[4];
    if (lane == 0) cnt[wv] = 0u;
    #pragma unroll 8
    for (int i = 0; i < 64; i++){
        const int m = i*64 + lane;
        f32x4 c = pb[m];
        float d = fmaf(ax, c[0], fmaf(ay, c[1], fmaf(az, c[2], c[3])));
        unsigned int u = mono(d);
        if (u < vhi || (u == vhi && (unsigned int)m <= vlo)){
            unsigned int slot = atomicAdd(&cnt[wv], 1u);
            if (slot < CAPW)
                cand[wv][slot] = (((unsigned long long)u) << 12) | (unsigned int)m;
        }
    }
    const unsigned int C = cnt[wv];
    if (C <= CAPW){
        for (unsigned int i = lane; i < C; i += 64){
            unsigned long long mk = cand[wv][i];
            unsigned int rank = 0;
            for (unsigned int j = 0; j < C; j++) rank += (cand[wv][j] < mk) ? 1u : 0u;
            if (rank < K_) knn[(size_t)p*K_ + rank] = (int)(mk & 0xFFFull);
        }
    } else {
        unsigned long long last = 0ull;
        for (int it = 0; it < K_; it++){
            unsigned long long cm = ~0ull;
            #pragma unroll 4
            for (int i = 0; i < 64; i++){
                const int m = i*64 + lane;
                f32x4 c = pb[m];
                float d = fmaf(ax, c[0], fmaf(ay, c[1], fmaf(az, c[2], c[3])));
                unsigned long long key = (((unsigned long long)mono(d)) << 12) | (unsigned int)m;
                if (key > last && key < cm) cm = key;
            }
            #pragma unroll
            for (int off = 32; off; off >>= 1){
                unsigned long long o = __shfl_xor(cm, off, 64);
                cm = o < cm ? o : cm;
            }
            if (lane == 0) knn[(size_t)p*K_ + it] = (int)(cm & 0xFFFull);
            last = cm;
        }
    }
}

// ---------------- MFMA GEMM: 128x128 tile, BK=32, global_load_lds double buffer ----
// 4 waves, each owns a 64x64 quadrant (4x4 fragments of 16x16x32).
// MODE 0: bias by 256-col range (e0|e1|e2) -> bf16 Y
// MODE 1: *scale(bn)+shift, relu -> bf16 Y
// MODE 2: +bias(e0) + residual featA, write fp32 out transposed (B,C,N)
template<int MODE>
__global__ __launch_bounds__(256) void k_gemm(
    const unsigned short* __restrict__ X, int ldx,
    const unsigned short* __restrict__ W, int Kin,
    const float* __restrict__ e0, const float* __restrict__ e1, const float* __restrict__ e2,
    unsigned short* __restrict__ Y, int ldy,
    const float* __restrict__ resid, float* __restrict__ out)
{
    __shared__ __align__(16) unsigned short As[2][128*32];
    __shared__ __align__(16) unsigned short Bs[2][128*32];
    const int tid = threadIdx.x, wid = tid >> 6, lane = tid & 63;
    const int lr = lane & 15, lg = lane >> 4;
    const int wr = wid >> 1, wc = wid & 1;
    const int m0 = blockIdx.x*128, n0 = blockIdx.y*128;
    const int lrow = lane >> 2, lcol = (lane & 3)*8;   // one instr: 16 rows x 32 cols

    const unsigned short* Ag0 = X + (size_t)(m0 + wid*32 + lrow)*ldx + lcol;
    const unsigned short* Ag1 = X + (size_t)(m0 + wid*32 + 16 + lrow)*ldx + lcol;
    const unsigned short* Bg0 = W + (size_t)(n0 + wid*32 + lrow)*Kin + lcol;
    const unsigned short* Bg1 = W + (size_t)(n0 + wid*32 + 16 + lrow)*Kin + lcol;

    f32x4 acc[4][4] = {};
    const int NT = Kin >> 5;
    int buf = 0;
    gload_lds16(Ag0, &As[0][(wid*32)*32]);
    gload_lds16(Ag1, &As[0][(wid*32+16)*32]);
    gload_lds16(Bg0, &Bs[0][(wid*32)*32]);
    gload_lds16(Bg1, &Bs[0][(wid*32+16)*32]);
    __syncthreads();
    for (int kt = 0; kt < NT; kt++){
        if (kt + 1 < NT){
            const int k = (kt+1)*32;
            gload_lds16(Ag0 + k, &As[buf^1][(wid*32)*32]);
            gload_lds16(Ag1 + k, &As[buf^1][(wid*32+16)*32]);
            gload_lds16(Bg0 + k, &Bs[buf^1][(wid*32)*32]);
            gload_lds16(Bg1 + k, &Bs[buf^1][(wid*32+16)*32]);
        }
        bf16x8 a[4], b[4];
        #pragma unroll
        for (int mi = 0; mi < 4; mi++)
            a[mi] = *(const bf16x8*)&As[buf][(wr*64 + mi*16 + lr)*32 + lg*8];
        #pragma unroll
        for (int ni = 0; ni < 4; ni++)
            b[ni] = *(const bf16x8*)&Bs[buf][(wc*64 + ni*16 + lr)*32 + lg*8];
        #pragma unroll
        for (int mi = 0; mi < 4; mi++){
            #pragma unroll
            for (int ni = 0; ni < 4; ni++)
                acc[mi][ni] = __builtin_amdgcn_mfma_f32_16x16x32_bf16(a[mi], b[ni], acc[mi][ni], 0, 0, 0);
        }
        __syncthreads();
        buf ^= 1;
    }
    #pragma unroll
    for (int mi = 0; mi < 4; mi++){
        const int pbase = m0 + wr*64 + mi*16 + lg*4;
        #pragma unroll
        for (int ni = 0; ni < 4; ni++){
            const int o = n0 + wc*64 + ni*16 + lr;
            if (MODE == 0){
                const float* bp = (o < 256) ? e0 : ((o < 512) ? e1 : e2);
                float bias = bp[o & 255];
                #pragma unroll
                for (int r = 0; r < 4; r++)
                    Y[(size_t)(pbase + r)*ldy + o] = f2bf(acc[mi][ni][r] + bias);
            } else if (MODE == 1){
                float sc = e0[o] * 0.9999950000374997f;   // rsqrt(1+1e-5)*bn_g
                float sh = e1[o];
                #pragma unroll
                for (int r = 0; r < 4; r++){
                    float vv = fmaf(acc[mi][ni][r], sc, sh);
                    Y[(size_t)(pbase + r)*ldy + o] = f2bf(fmaxf(vv, 0.f));
                }
            } else {
                float bias = e0[o];
                const int b = pbase >> 12, nn = pbase & 4095;
                const size_t adr = ((size_t)b*C_ + o)*N_ + nn;
                f32x4 rv = *(const f32x4*)(resid + adr);
                f32x4 ov;
                #pragma unroll
                for (int r = 0; r < 4; r++) ov[r] = acc[mi][ni][r] + bias + rv[r];
                *(f32x4*)(out + adr) = ov;
            }
        }
    }
}

// ---------------- dual-path neighbor attention: 2 waves per point (head halves) ----
// Morton-ordered work assignment: XCD (bid&7) -> {batch, quarter of sorted order}.
// PV: all 8 gather loads issued before any FMA (full-depth prefetch).
__global__ __launch_bounds__(256) void k_attn(
    const unsigned short* __restrict__ QQ, const unsigned short* __restrict__ KVD,
    const int* __restrict__ KNN, const int* __restrict__ order,
    const float* __restrict__ lnsw, const float* __restrict__ lnsb,
    const float* __restrict__ lndw, const float* __restrict__ lndb,
    unsigned short* __restrict__ F)
{
    __shared__ float q_l[2][2][2][128];       // [ps][wh][sim/dis][dim]
    __shared__ float w_l[2][2][2][4][33];     // [ps][wh][path][h_local][k]
    __shared__ int   idx_l[2][2][32];         // per-wave copy -> no stage barrier
    __shared__ float part_l[2][2][4];

    const int tid = threadIdx.x;
    const int wid = tid >> 6, lane = tid & 63;
    const int ps = wid >> 1, wh = wid & 1;
    const int bid = blockIdx.x;                 // 4096 blocks
    const int xcd = bid & 7, ib = bid >> 3;
    const int batch = xcd & 1, quarter = xcd >> 1;
    const int jj = quarter*1024 + ib*2 + ps;
    const int p = order[(batch << 12) + jj];
    const int b = batch;

    {
        const unsigned short* qrow = QQ + (size_t)p*512 + wh*128 + lane*2;
        unsigned int us = *(const unsigned int*)qrow;
        unsigned int ud = *(const unsigned int*)(qrow + 256);
        q_l[ps][wh][0][lane*2]   = bf2f((unsigned short)(us & 0xffff));
        q_l[ps][wh][0][lane*2+1] = bf2f((unsigned short)(us >> 16));
        q_l[ps][wh][1][lane*2]   = bf2f((unsigned short)(ud & 0xffff));
        q_l[ps][wh][1][lane*2+1] = bf2f((unsigned short)(ud >> 16));
        if (lane < 32) idx_l[ps][wh][lane] = KNN[(size_t)p*K_ + lane];
    }
    // all LDS below is wave-local: no barrier needed until the LN combine

    const int hh = lane >> 5, kk = lane & 31;
    {
        const int nbr = idx_l[ps][wh][kk];
        const unsigned short* rowb = KVD + (size_t)((b<<12) + nbr)*768;
        bf16x8 kx[2][4], dx[2][4];
        #pragma unroll
        for (int j = 0; j < 2; j++){
            const int h = wh*4 + j*2 + hh;
            const bf16x8* kr = (const bf16x8*)(rowb + h*32);
            const bf16x8* dr = (const bf16x8*)(rowb + 512 + h*32);
            #pragma unroll
            for (int c = 0; c < 4; c++){ kx[j][c] = kr[c]; dx[j][c] = dr[c]; }
        }
        #pragma unroll
        for (int j = 0; j < 2; j++){
            const int hl = j*2 + hh;
            const float* qs = &q_l[ps][wh][0][hl*32];
            const float* qd = &q_l[ps][wh][1][hl*32];
            float s = 0.f, dd = 0.f;
            #pragma unroll
            for (int c = 0; c < 4; c++){
                #pragma unroll
                for (int e = 0; e < 8; e++){
                    const int d = c*8 + e;
                    s = fmaf(qs[d], bf2f((unsigned short)kx[j][c][e]), s);
                    float df = qd[d] - bf2f((unsigned short)dx[j][c][e]);
                    dd = fmaf(df, df, dd);
                }
            }
            float sim = s * 0.17677669529663687f;   // 1/sqrt(32)
            float dist = sqrtf(dd);
            float m1 = sim, m2 = dist;
            #pragma unroll
            for (int off = 1; off < 32; off <<= 1){
                m1 = fmaxf(m1, __shfl_xor(m1, off, 64));
                m2 = fmaxf(m2, __shfl_xor(m2, off, 64));
            }
            float e1v = __expf(sim - m1);
            float e2v = __expf(dist - m2);
            float s1 = e1v, s2 = e2v;
            #pragma unroll
            for (int off = 1; off < 32; off <<= 1){
                s1 += __shfl_xor(s1, off, 64);
                s2 += __shfl_xor(s2, off, 64);
            }
            w_l[ps][wh][0][hl][kk] = e1v / s1;
            w_l[ps][wh][1][hl][kk] = e2v / s2;
        }
    }

    const int tq = lane >> 4, c = lane & 15;
    const int hl = c >> 2;
    float cs[8] = {0,0,0,0,0,0,0,0}, cd[8] = {0,0,0,0,0,0,0,0};
    {
        const unsigned short* vbase = KVD + 256 + wh*128 + c*8;
        int nb[8];
        #pragma unroll
        for (int i = 0; i < 8; i++) nb[i] = idx_l[ps][wh][tq + i*4];
        bf16x8 vx[8];
        #pragma unroll
        for (int i = 0; i < 8; i++)
            vx[i] = *(const bf16x8*)(vbase + (size_t)((b<<12) + nb[i])*768);
        #pragma unroll
        for (int i = 0; i < 8; i++){
            const int t = tq + i*4;
            const float wsv = w_l[ps][wh][0][hl][t];
            const float wdv = w_l[ps][wh][1][hl][t];
            #pragma unroll
            for (int e = 0; e < 8; e++){
                float vf = bf2f((unsigned short)vx[i][e]);
                cs[e] = fmaf(wsv, vf, cs[e]);
                cd[e] = fmaf(wdv, vf, cd[e]);
            }
        }
    }
    #pragma unroll
    for (int e = 0; e < 8; e++){
        cs[e] += __shfl_xor(cs[e], 16, 64); cs[e] += __shfl_xor(cs[e], 32, 64);
        cd[e] += __shfl_xor(cd[e], 16, 64); cd[e] += __shfl_xor(cd[e], 32, 64);
    }
    float s1 = 0.f, q1 = 0.f, s2 = 0.f, q2 = 0.f;
    #pragma unroll
    for (int e = 0; e < 8; e++){
        s1 += cs[e]; q1 = fmaf(cs[e], cs[e], q1);
        s2 += cd[e]; q2 = fmaf(cd[e], cd[e], q2);
    }
    #pragma unroll
    for (int off = 1; off < 16; off <<= 1){
        s1 += __shfl_xor(s1, off, 64); q1 += __shfl_xor(q1, off, 64);
        s2 += __shfl_xor(s2, off, 64); q2 += __shfl_xor(q2, off, 64);
    }
    if (lane == 0){
        part_l[ps][wh][0] = s1; part_l[ps][wh][1] = q1;
        part_l[ps][wh][2] = s2; part_l[ps][wh][3] = q2;
    }
    __syncthreads();
    const float S1 = s1 + part_l[ps][wh^1][0];
    const float Q1 = q1 + part_l[ps][wh^1][1];
    const float S2 = s2 + part_l[ps][wh^1][2];
    const float Q2 = q2 + part_l[ps][wh^1][3];
    const float m1 = S1*(1.f/256.f), m2 = S2*(1.f/256.f);
    const float r1 = rsqrtf(Q1*(1.f/256.f) - m1*m1 + 1e-5f);
    const float r2 = rsqrtf(Q2*(1.f/256.f) - m2*m2 + 1e-5f);

    if (tq == 0){
        bf16x8 ob;
        #pragma unroll
        for (int e = 0; e < 8; e++){
            const int cg = wh*128 + c*8 + e;
            ob[e] = (short)f2bf((cs[e]-m1)*r1*lnsw[cg] + lnsb[cg]);
        }
        *(bf16x8*)(F + (size_t)p*768 + 256 + wh*128 + c*8) = ob;
    } else if (tq == 1){
        bf16x8 ob;
        #pragma unroll
        for (int e = 0; e < 8; e++){
            const int cg = wh*128 + c*8 + e;
            ob[e] = (short)f2bf((cd[e]-m2)*r2*lndw[cg] + lndb[cg]);
        }
        *(bf16x8*)(F + (size_t)p*768 + 512 + wh*128 + c*8) = ob;
    }
}

extern "C" void kernel_launch(void* const* d_in, const int* in_sizes, int n_in,
                              void* d_out, int out_size, void* d_ws, size_t ws_size,
                              hipStream_t stream)
{
    const float* xyzA   = (const float*)d_in[0];
    const float* xyzB   = (const float*)d_in[1];
    const float* featA  = (const float*)d_in[2];
    const float* featB  = (const float*)d_in[3];
    const float* ln_in_w= (const float*)d_in[4];
    const float* ln_in_b= (const float*)d_in[5];
    const float* wq  = (const float*)d_in[6];
    const float* bq  = (const float*)d_in[7];
    const float* wk  = (const float*)d_in[8];
    const float* bk  = (const float*)d_in[9];
    const float* wv  = (const float*)d_in[10];
    const float* bv  = (const float*)d_in[11];
    const float* wqd = (const float*)d_in[12];
    const float* bqd = (const float*)d_in[13];
    const float* wkd = (const float*)d_in[14];
    const float* bkd = (const float*)d_in[15];
    const float* lnsw = (const float*)d_in[16];
    const float* lnsb = (const float*)d_in[17];
    const float* lndw = (const float*)d_in[18];
    const float* lndb = (const float*)d_in[19];
    const float* fw1 = (const float*)d_in[20];
    const float* bng = (const float*)d_in[21];
    const float* bnb = (const float*)d_in[22];
    const float* fw2 = (const float*)d_in[23];
    const float* fb2 = (const float*)d_in[24];
    float* out = (float*)d_out;
    char* ws = (char*)d_ws;

    unsigned short* F    = (unsigned short*)(ws + 0);          // 8192*768 bf16
    unsigned short* XBT  = (unsigned short*)(ws + 12582912);   // 8192*256
    unsigned short* QQ   = (unsigned short*)(ws + 16777216);   // 8192*512
    unsigned short* KVD  = (unsigned short*)(ws + 25165824);   // 8192*768
    unsigned short* Y1   = (unsigned short*)(ws + 37748736);   // 8192*512 (GEMM) ; PB (knn, earlier)
    f32x4*          PB   = (f32x4*)(ws + 37748736);            // 8192*16B, dead before fus1
    int*            KNNi = (int*)(ws + 46137344);              // 8192*32
    int*            ORD  = (int*)(ws + 47185920);              // 8192*4 = 32KB
    unsigned short* Wb   = (unsigned short*)(ws + 47251456);   // 851968 bf16
    unsigned short* WQcat = Wb;                // 512x256
    unsigned short* WKVD  = Wb + 131072;       // 768x256
    unsigned short* W1b   = Wb + 327680;       // 512x768
    unsigned short* W2b   = Wb + 720896;       // 256x512

    k_cvt_all<<<3328, 256, 0, stream>>>(wq, wqd, wk, wv, wkd, fw1, fw2, Wb);
    k_prep<<<32, 256, 0, stream>>>(xyzB, PB);
    k_morton<<<2, 256, 0, stream>>>(xyzA, ORD);

    k_lnt<<<256, 256, 0, stream>>>(featA, ln_in_w, ln_in_b, F);
    k_transpose<<<dim3(64,4,2), 256, 0, stream>>>(featB, XBT);
    k_knn<<<2048, 256, 0, stream>>>(xyzA, PB, KNNi);

    k_gemm<0><<<dim3(64,4), 256, 0, stream>>>(F,   768, WQcat, 256, bq, bqd, nullptr, QQ, 512, nullptr, nullptr);
    k_gemm<0><<<dim3(64,6), 256, 0, stream>>>(XBT, 256, WKVD, 256, bk, bv, bkd, KVD, 768, nullptr, nullptr);

    k_attn<<<4096, 256, 0, stream>>>(QQ, KVD, KNNi, ORD, lnsw, lnsb, lndw, lndb, F);

    k_gemm<1><<<dim3(64,4), 256, 0, stream>>>(F,  768, W1b, 768, bng, bnb, nullptr, Y1, 512, nullptr, nullptr);
    k_gemm<2><<<dim3(64,2), 256, 0, stream>>>(Y1, 512, W2b, 512, fb2, nullptr, nullptr, nullptr, 0, featA, out);
}

// Round 10
// 149.055 us; speedup vs baseline: 1.3364x; 1.1160x over previous
//
#include <hip/hip_runtime.h>
#include <hip/hip_bf16.h>
#include <math.h>

#define B_ 2
#define N_ 4096
#define C_ 256
#define H_ 8
#define K_ 32
#define NP_ (B_*N_)
#define CAPW 256

typedef __attribute__((ext_vector_type(8))) short bf16x8;
typedef __attribute__((ext_vector_type(4))) float f32x4;

__device__ __forceinline__ float bf2f(unsigned short v){
    union { unsigned int u; float f; } x; x.u = ((unsigned int)v) << 16; return x.f;
}
__device__ __forceinline__ unsigned short f2bf(float f){
    union { float f; unsigned int u; } x; x.f = f;
    return (unsigned short)((x.u + 0x7FFFu + ((x.u >> 16) & 1u)) >> 16);
}
__device__ __forceinline__ unsigned int mono(float f){
    union { float f; unsigned int u; } x; x.f = f;
    return x.u ^ (0x80000000u | (unsigned int)((int)x.u >> 31));
}
__device__ __forceinline__ void gload_lds16(const unsigned short* g, unsigned short* l){
    __builtin_amdgcn_global_load_lds(
        (const __attribute__((address_space(1))) unsigned int*)g,
        (__attribute__((address_space(3))) unsigned int*)l, 16, 0, 0);
}

// ================= mega-prologue: cvt | prep | morton | lnt | transposeB =========
// block ranges: [0,3328) cvt, [3328,3360) prep, [3360,3362) morton,
//               [3362,3618) lnt, [3618,4130) transposeB
__global__ __launch_bounds__(256) void k_pre(
    const float* __restrict__ s0, const float* __restrict__ s1,
    const float* __restrict__ s2, const float* __restrict__ s3,
    const float* __restrict__ s4, const float* __restrict__ s5,
    const float* __restrict__ s6, unsigned short* __restrict__ Wb,
    const float* __restrict__ xyzB, f32x4* __restrict__ PB,
    const float* __restrict__ xyzA, int* __restrict__ order,
    const float* __restrict__ featA, const float* __restrict__ lnw,
    const float* __restrict__ lnb, unsigned short* __restrict__ F,
    const float* __restrict__ featB, unsigned short* __restrict__ XBT)
{
    __shared__ __align__(16) char smem[35200];
    const int bid = blockIdx.x;
    const int tid = threadIdx.x;
    if (bid < 3328){
        // ---- weight fp32 -> bf16 ----
        int i = bid*256 + tid;
        float v;
        if (i < 327680){
            int seg = i >> 16, off = i & 65535;
            const float* s = (seg==0)?s0:(seg==1)?s1:(seg==2)?s2:(seg==3)?s3:s4;
            v = s[off];
        } else if (i < 720896){
            v = s5[i - 327680];
        } else {
            v = s6[i - 720896];
        }
        Wb[i] = f2bf(v);
    } else if (bid < 3360){
        // ---- pack xyzB ----
        int i = (bid - 3328)*256 + tid;
        float x = xyzB[i*3], y = xyzB[i*3+1], z = xyzB[i*3+2];
        f32x4 o;
        o[0] = -2.f*x; o[1] = -2.f*y; o[2] = -2.f*z;
        o[3] = x*x + y*y + z*z;
        PB[i] = o;
    } else if (bid < 3362){
        // ---- morton bucket order ----
        unsigned int* hist = (unsigned int*)smem;
        unsigned int* wsum = (unsigned int*)(smem + 4096);
        const int b = bid - 3360;
        const int wv = tid >> 6, lane = tid & 63;
        for (int i = tid; i < 1024; i += 256) hist[i] = 0u;
        __syncthreads();
        unsigned int code[16];
        #pragma unroll
        for (int i = 0; i < 16; i++){
            const int n = tid + i*256;
            const float* pp = xyzA + (size_t)((b<<12) + n)*3;
            int qx = (int)fminf(fmaxf((pp[0] + 5.f)*1.6f, 0.f), 15.f);
            int qy = (int)fminf(fmaxf((pp[1] + 5.f)*0.8f, 0.f), 7.f);
            int qz = (int)fminf(fmaxf((pp[2] + 5.f)*0.8f, 0.f), 7.f);
            unsigned int c = (unsigned int)((qx & 1) | ((qz & 1) << 1) | ((qy & 1) << 2)
                           | (((qx >> 1) & 1) << 3) | (((qz >> 1) & 1) << 4) | (((qy >> 1) & 1) << 5)
                           | (((qx >> 2) & 1) << 6) | (((qz >> 2) & 1) << 7) | (((qy >> 2) & 1) << 8)
                           | (((qx >> 3) & 1) << 9));
            code[i] = c;
            atomicAdd(&hist[c], 1u);
        }
        __syncthreads();
        unsigned int loc[4], t4 = 0;
        #pragma unroll
        for (int j = 0; j < 4; j++){ loc[j] = hist[tid*4 + j]; t4 += loc[j]; }
        unsigned int sc = t4;
        #pragma unroll
        for (int off = 1; off < 64; off <<= 1){
            unsigned int o = __shfl_up(sc, off, 64);
            if (lane >= off) sc += o;
        }
        if (lane == 63) wsum[wv] = sc;
        __syncthreads();
        unsigned int wb = 0;
        #pragma unroll
        for (int j = 0; j < 4; j++) if (j < wv) wb += wsum[j];
        unsigned int base = wb + sc - t4;
        #pragma unroll
        for (int j = 0; j < 4; j++){ hist[tid*4 + j] = base; base += loc[j]; }
        __syncthreads();
        #pragma unroll
        for (int i = 0; i < 16; i++){
            const int n = tid + i*256;
            unsigned int pos = atomicAdd(&hist[code[i]], 1u);
            order[(b<<12) + pos] = (b<<12) | n;
        }
    } else if (bid < 3618){
        // ---- fused LN(featA)+transpose -> F cols 0..255 ----
        float (*tile)[257] = (float(*)[257])smem;
        float (*ps)[32]    = (float(*)[32])(smem + 32896);
        float (*pq)[32]    = (float(*)[32])(smem + 33920);
        float (*st)[32]    = (float(*)[32])(smem + 34944);
        const int nx = tid & 31, cy = tid >> 5;
        const int pbase = (bid - 3362) * 32;
        const int b = pbase >> 12, n0 = pbase & 4095;
        const float* sp = featA + (size_t)b*C_*N_ + n0;
        #pragma unroll 4
        for (int it = 0; it < 32; it++){
            int c = cy + it*8;
            tile[nx][c] = sp[(size_t)c*N_ + nx];
        }
        __syncthreads();
        {
            float s = 0.f, q = 0.f;
            #pragma unroll 8
            for (int i = 0; i < 32; i++){
                int cc = cy*32 + ((i + cy) & 31);
                float x = tile[nx][cc];
                s += x; q = fmaf(x, x, q);
            }
            ps[cy][nx] = s; pq[cy][nx] = q;
        }
        __syncthreads();
        if (tid < 32){
            float S = 0.f, Q = 0.f;
            #pragma unroll
            for (int j = 0; j < 8; j++){ S += ps[j][tid]; Q += pq[j][tid]; }
            float m = S*(1.f/256.f);
            float v = Q*(1.f/256.f) - m*m;
            st[0][tid] = m; st[1][tid] = rsqrtf(v + 1e-5f);
        }
        __syncthreads();
        const int p = pbase + nx;
        const float m = st[0][nx], r = st[1][nx];
        #pragma unroll
        for (int j = 0; j < 4; j++){
            bf16x8 ob;
            #pragma unroll
            for (int e = 0; e < 8; e++){
                int c = cy*32 + j*8 + e;
                ob[e] = (short)f2bf((tile[nx][c]-m)*r*lnw[c] + lnb[c]);
            }
            *(bf16x8*)(F + (size_t)p*768 + cy*32 + j*8) = ob;
        }
    } else {
        // ---- transpose featB -> XBT ----
        float (*tile)[65] = (float(*)[65])smem;
        const int idx = bid - 3618;
        const int x = idx & 63, y = (idx >> 6) & 3, z = idx >> 8;
        const int n0 = x*64, c0 = y*64;
        const int tx = tid & 63, ty = tid >> 6;
        const float* sp = featB + (size_t)z*C_*N_;
        #pragma unroll
        for (int i = 0; i < 16; i++){
            int cr = ty + i*4;
            tile[cr][tx] = sp[(size_t)(c0+cr)*N_ + n0 + tx];
        }
        __syncthreads();
        const int c = c0 + tx;
        #pragma unroll
        for (int i = 0; i < 16; i++){
            int nr = ty + i*4;
            int p = (z<<12) + n0 + nr;
            XBT[(size_t)p*256 + c] = f2bf(tile[tx][nr]);
        }
    }
}

// ---------------- KNN: storage-free two-pass, one query per wave ----------------
__global__ __launch_bounds__(256) void k_knn(const float* __restrict__ xyzA,
        const f32x4* __restrict__ PB, int* __restrict__ knn){
    const int wv = threadIdx.x >> 6, lane = threadIdx.x & 63;
    const int p = blockIdx.x*4 + wv;
    const int b = p >> 12;
    const f32x4* pb = PB + ((size_t)b << 12);
    const float ax = xyzA[(size_t)p*3], ay = xyzA[(size_t)p*3+1], az = xyzA[(size_t)p*3+2];

    unsigned long long mn = ~0ull;
    #pragma unroll 8
    for (int i = 0; i < 64; i++){
        const int m = i*64 + lane;
        f32x4 c = pb[m];
        float d = fmaf(ax, c[0], fmaf(ay, c[1], fmaf(az, c[2], c[3])));
        unsigned long long key = (((unsigned long long)mono(d)) << 12) | (unsigned int)m;
        mn = key < mn ? key : mn;
    }
    unsigned int rk = 0;
    for (int j = 0; j < 64; j++){
        unsigned long long o = __shfl(mn, j, 64);
        rk += (o < mn) ? 1u : 0u;
    }
    unsigned long long sel = (rk == 31u) ? mn : ~0ull;
    #pragma unroll
    for (int off = 32; off; off >>= 1){
        unsigned long long o = __shfl_xor(sel, off, 64);
        sel = o < sel ? o : sel;
    }
    const unsigned long long v = sel;
    const unsigned int vhi = (unsigned int)(v >> 12);
    const unsigned int vlo = (unsigned int)(v & 0xFFFull);

    __shared__ unsigned long long cand[4][CAPW];
    __shared__ unsigned int cnt[4];
    if (lane == 0) cnt[wv] = 0u;
    #pragma unroll 8
    for (int i = 0; i < 64; i++){
        const int m = i*64 + lane;
        f32x4 c = pb[m];
        float d = fmaf(ax, c[0], fmaf(ay, c[1], fmaf(az, c[2], c[3])));
        unsigned int u = mono(d);
        if (u < vhi || (u == vhi && (unsigned int)m <= vlo)){
            unsigned int slot = atomicAdd(&cnt[wv], 1u);
            if (slot < CAPW)
                cand[wv][slot] = (((unsigned long long)u) << 12) | (unsigned int)m;
        }
    }
    const unsigned int C = cnt[wv];
    if (C <= CAPW){
        for (unsigned int i = lane; i < C; i += 64){
            unsigned long long mk = cand[wv][i];
            unsigned int rank = 0;
            for (unsigned int j = 0; j < C; j++) rank += (cand[wv][j] < mk) ? 1u : 0u;
            if (rank < K_) knn[(size_t)p*K_ + rank] = (int)(mk & 0xFFFull);
        }
    } else {
        unsigned long long last = 0ull;
        for (int it = 0; it < K_; it++){
            unsigned long long cm = ~0ull;
            #pragma unroll 4
            for (int i = 0; i < 64; i++){
                const int m = i*64 + lane;
                f32x4 c = pb[m];
                float d = fmaf(ax, c[0], fmaf(ay, c[1], fmaf(az, c[2], c[3])));
                unsigned long long key = (((unsigned long long)mono(d)) << 12) | (unsigned int)m;
                if (key > last && key < cm) cm = key;
            }
            #pragma unroll
            for (int off = 32; off; off >>= 1){
                unsigned long long o = __shfl_xor(cm, off, 64);
                cm = o < cm ? o : cm;
            }
            if (lane == 0) knn[(size_t)p*K_ + it] = (int)(cm & 0xFFFull);
            last = cm;
        }
    }
}

// ---------------- MFMA GEMM body: 128x128 tile, BK=32, gload_lds double buffer ----
template<int MODE>
__device__ __forceinline__ void gemm_body(
    const unsigned short* __restrict__ X, int ldx,
    const unsigned short* __restrict__ W, int Kin,
    const float* __restrict__ e0, const float* __restrict__ e1, const float* __restrict__ e2,
    unsigned short* __restrict__ Y, int ldy,
    const float* __restrict__ resid, float* __restrict__ out,
    unsigned short (*As)[128*32], unsigned short (*Bs)[128*32], int bx, int by)
{
    const int tid = threadIdx.x, wid = tid >> 6, lane = tid & 63;
    const int lr = lane & 15, lg = lane >> 4;
    const int wr = wid >> 1, wc = wid & 1;
    const int m0 = bx*128, n0 = by*128;
    const int lrow = lane >> 2, lcol = (lane & 3)*8;

    const unsigned short* Ag0 = X + (size_t)(m0 + wid*32 + lrow)*ldx + lcol;
    const unsigned short* Ag1 = X + (size_t)(m0 + wid*32 + 16 + lrow)*ldx + lcol;
    const unsigned short* Bg0 = W + (size_t)(n0 + wid*32 + lrow)*Kin + lcol;
    const unsigned short* Bg1 = W + (size_t)(n0 + wid*32 + 16 + lrow)*Kin + lcol;

    f32x4 acc[4][4] = {};
    const int NT = Kin >> 5;
    int buf = 0;
    gload_lds16(Ag0, &As[0][(wid*32)*32]);
    gload_lds16(Ag1, &As[0][(wid*32+16)*32]);
    gload_lds16(Bg0, &Bs[0][(wid*32)*32]);
    gload_lds16(Bg1, &Bs[0][(wid*32+16)*32]);
    __syncthreads();
    for (int kt = 0; kt < NT; kt++){
        if (kt + 1 < NT){
            const int k = (kt+1)*32;
            gload_lds16(Ag0 + k, &As[buf^1][(wid*32)*32]);
            gload_lds16(Ag1 + k, &As[buf^1][(wid*32+16)*32]);
            gload_lds16(Bg0 + k, &Bs[buf^1][(wid*32)*32]);
            gload_lds16(Bg1 + k, &Bs[buf^1][(wid*32+16)*32]);
        }
        bf16x8 a[4], b[4];
        #pragma unroll
        for (int mi = 0; mi < 4; mi++)
            a[mi] = *(const bf16x8*)&As[buf][(wr*64 + mi*16 + lr)*32 + lg*8];
        #pragma unroll
        for (int ni = 0; ni < 4; ni++)
            b[ni] = *(const bf16x8*)&Bs[buf][(wc*64 + ni*16 + lr)*32 + lg*8];
        #pragma unroll
        for (int mi = 0; mi < 4; mi++){
            #pragma unroll
            for (int ni = 0; ni < 4; ni++)
                acc[mi][ni] = __builtin_amdgcn_mfma_f32_16x16x32_bf16(a[mi], b[ni], acc[mi][ni], 0, 0, 0);
        }
        __syncthreads();
        buf ^= 1;
    }
    #pragma unroll
    for (int mi = 0; mi < 4; mi++){
        const int pbase = m0 + wr*64 + mi*16 + lg*4;
        #pragma unroll
        for (int ni = 0; ni < 4; ni++){
            const int o = n0 + wc*64 + ni*16 + lr;
            if (MODE == 0){
                const float* bp = (o < 256) ? e0 : ((o < 512) ? e1 : e2);
                float bias = bp[o & 255];
                #pragma unroll
                for (int r = 0; r < 4; r++)
                    Y[(size_t)(pbase + r)*ldy + o] = f2bf(acc[mi][ni][r] + bias);
            } else if (MODE == 1){
                float sc = e0[o] * 0.9999950000374997f;
                float sh = e1[o];
                #pragma unroll
                for (int r = 0; r < 4; r++){
                    float vv = fmaf(acc[mi][ni][r], sc, sh);
                    Y[(size_t)(pbase + r)*ldy + o] = f2bf(fmaxf(vv, 0.f));
                }
            } else {
                float bias = e0[o];
                const int b = pbase >> 12, nn = pbase & 4095;
                const size_t adr = ((size_t)b*C_ + o)*N_ + nn;
                f32x4 rv = *(const f32x4*)(resid + adr);
                f32x4 ov;
                #pragma unroll
                for (int r = 0; r < 4; r++) ov[r] = acc[mi][ni][r] + bias + rv[r];
                *(f32x4*)(out + adr) = ov;
            }
        }
    }
}

// merged projection GEMMs: y<4 -> QQ = F*WQcat^T ; y>=4 -> KVD = XBT*WKVD^T
__global__ __launch_bounds__(256) void k_proj(
    const unsigned short* __restrict__ F, const unsigned short* __restrict__ XBT,
    const unsigned short* __restrict__ WQcat, const unsigned short* __restrict__ WKVD,
    const float* __restrict__ bq, const float* __restrict__ bqd,
    const float* __restrict__ bk, const float* __restrict__ bv, const float* __restrict__ bkd,
    unsigned short* __restrict__ QQ, unsigned short* __restrict__ KVD)
{
    __shared__ __align__(16) unsigned short As[2][128*32];
    __shared__ __align__(16) unsigned short Bs[2][128*32];
    if (blockIdx.y < 4)
        gemm_body<0>(F, 768, WQcat, 256, bq, bqd, nullptr, QQ, 512, nullptr, nullptr,
                     As, Bs, blockIdx.x, blockIdx.y);
    else
        gemm_body<0>(XBT, 256, WKVD, 256, bk, bv, bkd, KVD, 768, nullptr, nullptr,
                     As, Bs, blockIdx.x, blockIdx.y - 4);
}

template<int MODE>
__global__ __launch_bounds__(256) void k_gemm(
    const unsigned short* __restrict__ X, int ldx,
    const unsigned short* __restrict__ W, int Kin,
    const float* __restrict__ e0, const float* __restrict__ e1, const float* __restrict__ e2,
    unsigned short* __restrict__ Y, int ldy,
    const float* __restrict__ resid, float* __restrict__ out)
{
    __shared__ __align__(16) unsigned short As[2][128*32];
    __shared__ __align__(16) unsigned short Bs[2][128*32];
    gemm_body<MODE>(X, ldx, W, Kin, e0, e1, e2, Y, ldy, resid, out,
                    As, Bs, blockIdx.x, blockIdx.y);
}

// ---------------- dual-path neighbor attention: ALL loads issued up front ----------
// 2 waves per point (head halves); Morton order; XCD (bid&7) -> {batch, quarter}.
__global__ __launch_bounds__(256) void k_attn(
    const unsigned short* __restrict__ QQ, const unsigned short* __restrict__ KVD,
    const int* __restrict__ KNN, const int* __restrict__ order,
    const float* __restrict__ lnsw, const float* __restrict__ lnsb,
    const float* __restrict__ lndw, const float* __restrict__ lndb,
    unsigned short* __restrict__ F)
{
    __shared__ float q_l[2][2][2][128];
    __shared__ float w_l[2][2][2][4][33];
    __shared__ int   idx_l[2][2][32];
    __shared__ float part_l[2][2][4];

    const int tid = threadIdx.x;
    const int wid = tid >> 6, lane = tid & 63;
    const int ps = wid >> 1, wh = wid & 1;
    const int bid = blockIdx.x;
    const int xcd = bid & 7, ib = bid >> 3;
    const int batch = xcd & 1, quarter = xcd >> 1;
    const int jj = quarter*1024 + ib*2 + ps;
    const int p = order[(batch << 12) + jj];
    const int b = batch;

    {
        const unsigned short* qrow = QQ + (size_t)p*512 + wh*128 + lane*2;
        unsigned int us = *(const unsigned int*)qrow;
        unsigned int ud = *(const unsigned int*)(qrow + 256);
        q_l[ps][wh][0][lane*2]   = bf2f((unsigned short)(us & 0xffff));
        q_l[ps][wh][0][lane*2+1] = bf2f((unsigned short)(us >> 16));
        q_l[ps][wh][1][lane*2]   = bf2f((unsigned short)(ud & 0xffff));
        q_l[ps][wh][1][lane*2+1] = bf2f((unsigned short)(ud >> 16));
        if (lane < 32) idx_l[ps][wh][lane] = KNN[(size_t)p*K_ + lane];
    }
    // wave-local LDS; lockstep + compiler lgkmcnt ordering, no block barrier needed yet

    const int hh = lane >> 5, kk = lane & 31;
    const int tq = lane >> 4, c = lane & 15;
    const int hl = c >> 2;

    // ======== issue ALL gather loads up front (24 outstanding vmem / lane) ========
    const int nbr_qk = idx_l[ps][wh][kk];
    int nbt[8];
    #pragma unroll
    for (int i = 0; i < 8; i++) nbt[i] = idx_l[ps][wh][tq + i*4];

    const unsigned short* rowb = KVD + (size_t)((b<<12) + nbr_qk)*768;
    bf16x8 kx[2][4], dx[2][4];
    #pragma unroll
    for (int j = 0; j < 2; j++){
        const int h = wh*4 + j*2 + hh;
        const bf16x8* kr = (const bf16x8*)(rowb + h*32);
        const bf16x8* dr = (const bf16x8*)(rowb + 512 + h*32);
        #pragma unroll
        for (int cc = 0; cc < 4; cc++){ kx[j][cc] = kr[cc]; dx[j][cc] = dr[cc]; }
    }
    const unsigned short* vbase = KVD + 256 + wh*128 + c*8;
    bf16x8 vx[8];
    #pragma unroll
    for (int i = 0; i < 8; i++)
        vx[i] = *(const bf16x8*)(vbase + (size_t)((b<<12) + nbt[i])*768);

    // ======== QK + dist + softmax ========
    #pragma unroll
    for (int j = 0; j < 2; j++){
        const int hloc = j*2 + hh;
        const float* qs = &q_l[ps][wh][0][hloc*32];
        const float* qd = &q_l[ps][wh][1][hloc*32];
        float s = 0.f, dd = 0.f;
        #pragma unroll
        for (int cc = 0; cc < 4; cc++){
            #pragma unroll
            for (int e = 0; e < 8; e++){
                const int d = cc*8 + e;
                s = fmaf(qs[d], bf2f((unsigned short)kx[j][cc][e]), s);
                float df = qd[d] - bf2f((unsigned short)dx[j][cc][e]);
                dd = fmaf(df, df, dd);
            }
        }
        float sim = s * 0.17677669529663687f;   // 1/sqrt(32)
        float dist = sqrtf(dd);
        float m1 = sim, m2 = dist;
        #pragma unroll
        for (int off = 1; off < 32; off <<= 1){
            m1 = fmaxf(m1, __shfl_xor(m1, off, 64));
            m2 = fmaxf(m2, __shfl_xor(m2, off, 64));
        }
        float e1v = __expf(sim - m1);
        float e2v = __expf(dist - m2);
        float s1 = e1v, s2 = e2v;
        #pragma unroll
        for (int off = 1; off < 32; off <<= 1){
            s1 += __shfl_xor(s1, off, 64);
            s2 += __shfl_xor(s2, off, 64);
        }
        w_l[ps][wh][0][hloc][kk] = e1v / s1;
        w_l[ps][wh][1][hloc][kk] = e2v / s2;
    }

    // ======== PV (operands already resident) ========
    float cs[8] = {0,0,0,0,0,0,0,0}, cd[8] = {0,0,0,0,0,0,0,0};
    #pragma unroll
    for (int i = 0; i < 8; i++){
        const int t = tq + i*4;
        const float wsv = w_l[ps][wh][0][hl][t];
        const float wdv = w_l[ps][wh][1][hl][t];
        #pragma unroll
        for (int e = 0; e < 8; e++){
            float vf = bf2f((unsigned short)vx[i][e]);
            cs[e] = fmaf(wsv, vf, cs[e]);
            cd[e] = fmaf(wdv, vf, cd[e]);
        }
    }
    #pragma unroll
    for (int e = 0; e < 8; e++){
        cs[e] += __shfl_xor(cs[e], 16, 64); cs[e] += __shfl_xor(cs[e], 32, 64);
        cd[e] += __shfl_xor(cd[e], 16, 64); cd[e] += __shfl_xor(cd[e], 32, 64);
    }
    float s1 = 0.f, q1 = 0.f, s2 = 0.f, q2 = 0.f;
    #pragma unroll
    for (int e = 0; e < 8; e++){
        s1 += cs[e]; q1 = fmaf(cs[e], cs[e], q1);
        s2 += cd[e]; q2 = fmaf(cd[e], cd[e], q2);
    }
    #pragma unroll
    for (int off = 1; off < 16; off <<= 1){
        s1 += __shfl_xor(s1, off, 64); q1 += __shfl_xor(q1, off, 64);
        s2 += __shfl_xor(s2, off, 64); q2 += __shfl_xor(q2, off, 64);
    }
    if (lane == 0){
        part_l[ps][wh][0] = s1; part_l[ps][wh][1] = q1;
        part_l[ps][wh][2] = s2; part_l[ps][wh][3] = q2;
    }
    __syncthreads();
    const float S1 = s1 + part_l[ps][wh^1][0];
    const float Q1 = q1 + part_l[ps][wh^1][1];
    const float S2 = s2 + part_l[ps][wh^1][2];
    const float Q2 = q2 + part_l[ps][wh^1][3];
    const float m1 = S1*(1.f/256.f), m2 = S2*(1.f/256.f);
    const float r1 = rsqrtf(Q1*(1.f/256.f) - m1*m1 + 1e-5f);
    const float r2 = rsqrtf(Q2*(1.f/256.f) - m2*m2 + 1e-5f);

    if (tq == 0){
        bf16x8 ob;
        #pragma unroll
        for (int e = 0; e < 8; e++){
            const int cg = wh*128 + c*8 + e;
            ob[e] = (short)f2bf((cs[e]-m1)*r1*lnsw[cg] + lnsb[cg]);
        }
        *(bf16x8*)(F + (size_t)p*768 + 256 + wh*128 + c*8) = ob;
    } else if (tq == 1){
        bf16x8 ob;
        #pragma unroll
        for (int e = 0; e < 8; e++){
            const int cg = wh*128 + c*8 + e;
            ob[e] = (short)f2bf((cd[e]-m2)*r2*lndw[cg] + lndb[cg]);
        }
        *(bf16x8*)(F + (size_t)p*768 + 512 + wh*128 + c*8) = ob;
    }
}

extern "C" void kernel_launch(void* const* d_in, const int* in_sizes, int n_in,
                              void* d_out, int out_size, void* d_ws, size_t ws_size,
                              hipStream_t stream)
{
    const float* xyzA   = (const float*)d_in[0];
    const float* xyzB   = (const float*)d_in[1];
    const float* featA  = (const float*)d_in[2];
    const float* featB  = (const float*)d_in[3];
    const float* ln_in_w= (const float*)d_in[4];
    const float* ln_in_b= (const float*)d_in[5];
    const float* wq  = (const float*)d_in[6];
    const float* bq  = (const float*)d_in[7];
    const float* wk  = (const float*)d_in[8];
    const float* bk  = (const float*)d_in[9];
    const float* wv  = (const float*)d_in[10];
    const float* bv  = (const float*)d_in[11];
    const float* wqd = (const float*)d_in[12];
    const float* bqd = (const float*)d_in[13];
    const float* wkd = (const float*)d_in[14];
    const float* bkd = (const float*)d_in[15];
    const float* lnsw = (const float*)d_in[16];
    const float* lnsb = (const float*)d_in[17];
    const float* lndw = (const float*)d_in[18];
    const float* lndb = (const float*)d_in[19];
    const float* fw1 = (const float*)d_in[20];
    const float* bng = (const float*)d_in[21];
    const float* bnb = (const float*)d_in[22];
    const float* fw2 = (const float*)d_in[23];
    const float* fb2 = (const float*)d_in[24];
    float* out = (float*)d_out;
    char* ws = (char*)d_ws;

    unsigned short* F    = (unsigned short*)(ws + 0);          // 8192*768 bf16
    unsigned short* XBT  = (unsigned short*)(ws + 12582912);   // 8192*256
    unsigned short* QQ   = (unsigned short*)(ws + 16777216);   // 8192*512
    unsigned short* KVD  = (unsigned short*)(ws + 25165824);   // 8192*768
    unsigned short* Y1   = (unsigned short*)(ws + 37748736);   // 8192*512 ; PB earlier
    f32x4*          PB   = (f32x4*)(ws + 37748736);            // dead before fus1
    int*            KNNi = (int*)(ws + 46137344);              // 8192*32
    int*            ORD  = (int*)(ws + 47185920);              // 8192*4
    unsigned short* Wb   = (unsigned short*)(ws + 47251456);   // 851968 bf16
    unsigned short* WQcat = Wb;                // 512x256
    unsigned short* WKVD  = Wb + 131072;       // 768x256
    unsigned short* W1b   = Wb + 327680;       // 512x768
    unsigned short* W2b   = Wb + 720896;       // 256x512

    k_pre<<<4130, 256, 0, stream>>>(wq, wqd, wk, wv, wkd, fw1, fw2, Wb,
                                    xyzB, PB, xyzA, ORD,
                                    featA, ln_in_w, ln_in_b, F, featB, XBT);
    k_knn<<<2048, 256, 0, stream>>>(xyzA, PB, KNNi);

    k_proj<<<dim3(64,10), 256, 0, stream>>>(F, XBT, WQcat, WKVD, bq, bqd, bk, bv, bkd, QQ, KVD);

    k_attn<<<4096, 256, 0, stream>>>(QQ, KVD, KNNi, ORD, lnsw, lnsb, lndw, lndb, F);

    k_gemm<1><<<dim3(64,4), 256, 0, stream>>>(F,  768, W1b, 768, bng, bnb, nullptr, Y1, 512, nullptr, nullptr);
    k_gemm<2><<<dim3(64,2), 256, 0, stream>>>(Y1, 512, W2b, 512, fb2, nullptr, nullptr, nullptr, 0, featA, out);
}

// Round 11
// 141.966 us; speedup vs baseline: 1.4032x; 1.0499x over previous
//
#include <hip/hip_runtime.h>
#include <hip/hip_bf16.h>
#include <math.h>

#define B_ 2
#define N_ 4096
#define C_ 256
#define H_ 8
#define K_ 32
#define NP_ (B_*N_)
#define CAPW 256

typedef __attribute__((ext_vector_type(8))) short bf16x8;
typedef __attribute__((ext_vector_type(4))) float f32x4;

__device__ __forceinline__ float bf2f(unsigned short v){
    union { unsigned int u; float f; } x; x.u = ((unsigned int)v) << 16; return x.f;
}
__device__ __forceinline__ unsigned short f2bf(float f){
    union { float f; unsigned int u; } x; x.f = f;
    return (unsigned short)((x.u + 0x7FFFu + ((x.u >> 16) & 1u)) >> 16);
}
__device__ __forceinline__ unsigned int mono(float f){
    union { float f; unsigned int u; } x; x.f = f;
    return x.u ^ (0x80000000u | (unsigned int)((int)x.u >> 31));
}
__device__ __forceinline__ void gload_lds16(const unsigned short* g, unsigned short* l){
    __builtin_amdgcn_global_load_lds(
        (const __attribute__((address_space(1))) unsigned int*)g,
        (__attribute__((address_space(3))) unsigned int*)l, 16, 0, 0);
}

// ================= mega-prologue: cvt | prep | morton | lnt | transposeB =========
__global__ __launch_bounds__(256) void k_pre(
    const float* __restrict__ s0, const float* __restrict__ s1,
    const float* __restrict__ s2, const float* __restrict__ s3,
    const float* __restrict__ s4, const float* __restrict__ s5,
    const float* __restrict__ s6, unsigned short* __restrict__ Wb,
    const float* __restrict__ xyzB, f32x4* __restrict__ PB,
    const float* __restrict__ xyzA, int* __restrict__ order,
    const float* __restrict__ featA, const float* __restrict__ lnw,
    const float* __restrict__ lnb, unsigned short* __restrict__ F,
    const float* __restrict__ featB, unsigned short* __restrict__ XBT)
{
    __shared__ __align__(16) char smem[35200];
    const int bid = blockIdx.x;
    const int tid = threadIdx.x;
    if (bid < 3328){
        int i = bid*256 + tid;
        float v;
        if (i < 327680){
            int seg = i >> 16, off = i & 65535;
            const float* s = (seg==0)?s0:(seg==1)?s1:(seg==2)?s2:(seg==3)?s3:s4;
            v = s[off];
        } else if (i < 720896){
            v = s5[i - 327680];
        } else {
            v = s6[i - 720896];
        }
        Wb[i] = f2bf(v);
    } else if (bid < 3360){
        int i = (bid - 3328)*256 + tid;
        float x = xyzB[i*3], y = xyzB[i*3+1], z = xyzB[i*3+2];
        f32x4 o;
        o[0] = -2.f*x; o[1] = -2.f*y; o[2] = -2.f*z;
        o[3] = x*x + y*y + z*z;
        PB[i] = o;
    } else if (bid < 3362){
        unsigned int* hist = (unsigned int*)smem;
        unsigned int* wsum = (unsigned int*)(smem + 4096);
        const int b = bid - 3360;
        const int wv = tid >> 6, lane = tid & 63;
        for (int i = tid; i < 1024; i += 256) hist[i] = 0u;
        __syncthreads();
        unsigned int code[16];
        #pragma unroll
        for (int i = 0; i < 16; i++){
            const int n = tid + i*256;
            const float* pp = xyzA + (size_t)((b<<12) + n)*3;
            int qx = (int)fminf(fmaxf((pp[0] + 5.f)*1.6f, 0.f), 15.f);
            int qy = (int)fminf(fmaxf((pp[1] + 5.f)*0.8f, 0.f), 7.f);
            int qz = (int)fminf(fmaxf((pp[2] + 5.f)*0.8f, 0.f), 7.f);
            unsigned int c = (unsigned int)((qx & 1) | ((qz & 1) << 1) | ((qy & 1) << 2)
                           | (((qx >> 1) & 1) << 3) | (((qz >> 1) & 1) << 4) | (((qy >> 1) & 1) << 5)
                           | (((qx >> 2) & 1) << 6) | (((qz >> 2) & 1) << 7) | (((qy >> 2) & 1) << 8)
                           | (((qx >> 3) & 1) << 9));
            code[i] = c;
            atomicAdd(&hist[c], 1u);
        }
        __syncthreads();
        unsigned int loc[4], t4 = 0;
        #pragma unroll
        for (int j = 0; j < 4; j++){ loc[j] = hist[tid*4 + j]; t4 += loc[j]; }
        unsigned int sc = t4;
        #pragma unroll
        for (int off = 1; off < 64; off <<= 1){
            unsigned int o = __shfl_up(sc, off, 64);
            if (lane >= off) sc += o;
        }
        if (lane == 63) wsum[wv] = sc;
        __syncthreads();
        unsigned int wb = 0;
        #pragma unroll
        for (int j = 0; j < 4; j++) if (j < wv) wb += wsum[j];
        unsigned int base = wb + sc - t4;
        #pragma unroll
        for (int j = 0; j < 4; j++){ hist[tid*4 + j] = base; base += loc[j]; }
        __syncthreads();
        #pragma unroll
        for (int i = 0; i < 16; i++){
            const int n = tid + i*256;
            unsigned int pos = atomicAdd(&hist[code[i]], 1u);
            order[(b<<12) + pos] = (b<<12) | n;
        }
    } else if (bid < 3618){
        float (*tile)[257] = (float(*)[257])smem;
        float (*ps)[32]    = (float(*)[32])(smem + 32896);
        float (*pq)[32]    = (float(*)[32])(smem + 33920);
        float (*st)[32]    = (float(*)[32])(smem + 34944);
        const int nx = tid & 31, cy = tid >> 5;
        const int pbase = (bid - 3362) * 32;
        const int b = pbase >> 12, n0 = pbase & 4095;
        const float* sp = featA + (size_t)b*C_*N_ + n0;
        #pragma unroll 4
        for (int it = 0; it < 32; it++){
            int c = cy + it*8;
            tile[nx][c] = sp[(size_t)c*N_ + nx];
        }
        __syncthreads();
        {
            float s = 0.f, q = 0.f;
            #pragma unroll 8
            for (int i = 0; i < 32; i++){
                int cc = cy*32 + ((i + cy) & 31);
                float x = tile[nx][cc];
                s += x; q = fmaf(x, x, q);
            }
            ps[cy][nx] = s; pq[cy][nx] = q;
        }
        __syncthreads();
        if (tid < 32){
            float S = 0.f, Q = 0.f;
            #pragma unroll
            for (int j = 0; j < 8; j++){ S += ps[j][tid]; Q += pq[j][tid]; }
            float m = S*(1.f/256.f);
            float v = Q*(1.f/256.f) - m*m;
            st[0][tid] = m; st[1][tid] = rsqrtf(v + 1e-5f);
        }
        __syncthreads();
        const int p = pbase + nx;
        const float m = st[0][nx], r = st[1][nx];
        #pragma unroll
        for (int j = 0; j < 4; j++){
            bf16x8 ob;
            #pragma unroll
            for (int e = 0; e < 8; e++){
                int c = cy*32 + j*8 + e;
                ob[e] = (short)f2bf((tile[nx][c]-m)*r*lnw[c] + lnb[c]);
            }
            *(bf16x8*)(F + (size_t)p*768 + cy*32 + j*8) = ob;
        }
    } else {
        float (*tile)[65] = (float(*)[65])smem;
        const int idx = bid - 3618;
        const int x = idx & 63, y = (idx >> 6) & 3, z = idx >> 8;
        const int n0 = x*64, c0 = y*64;
        const int tx = tid & 63, ty = tid >> 6;
        const float* sp = featB + (size_t)z*C_*N_;
        #pragma unroll
        for (int i = 0; i < 16; i++){
            int cr = ty + i*4;
            tile[cr][tx] = sp[(size_t)(c0+cr)*N_ + n0 + tx];
        }
        __syncthreads();
        const int c = c0 + tx;
        #pragma unroll
        for (int i = 0; i < 16; i++){
            int nr = ty + i*4;
            int p = (z<<12) + n0 + nr;
            XBT[(size_t)p*256 + c] = f2bf(tile[tx][nr]);
        }
    }
}

// ---------------- KNN: storage-free two-pass, one query per wave ----------------
__global__ __launch_bounds__(256) void k_knn(const float* __restrict__ xyzA,
        const f32x4* __restrict__ PB, int* __restrict__ knn){
    const int wv = threadIdx.x >> 6, lane = threadIdx.x & 63;
    const int p = blockIdx.x*4 + wv;
    const int b = p >> 12;
    const f32x4* pb = PB + ((size_t)b << 12);
    const float ax = xyzA[(size_t)p*3], ay = xyzA[(size_t)p*3+1], az = xyzA[(size_t)p*3+2];

    unsigned long long mn = ~0ull;
    #pragma unroll 8
    for (int i = 0; i < 64; i++){
        const int m = i*64 + lane;
        f32x4 c = pb[m];
        float d = fmaf(ax, c[0], fmaf(ay, c[1], fmaf(az, c[2], c[3])));
        unsigned long long key = (((unsigned long long)mono(d)) << 12) | (unsigned int)m;
        mn = key < mn ? key : mn;
    }
    unsigned int rk = 0;
    for (int j = 0; j < 64; j++){
        unsigned long long o = __shfl(mn, j, 64);
        rk += (o < mn) ? 1u : 0u;
    }
    unsigned long long sel = (rk == 31u) ? mn : ~0ull;
    #pragma unroll
    for (int off = 32; off; off >>= 1){
        unsigned long long o = __shfl_xor(sel, off, 64);
        sel = o < sel ? o : sel;
    }
    const unsigned long long v = sel;
    const unsigned int vhi = (unsigned int)(v >> 12);
    const unsigned int vlo = (unsigned int)(v & 0xFFFull);

    __shared__ unsigned long long cand[4][CAPW];
    __shared__ unsigned int cnt[4];
    if (lane == 0) cnt[wv] = 0u;
    #pragma unroll 8
    for (int i = 0; i < 64; i++){
        const int m = i*64 + lane;
        f32x4 c = pb[m];
        float d = fmaf(ax, c[0], fmaf(ay, c[1], fmaf(az, c[2], c[3])));
        unsigned int u = mono(d);
        if (u < vhi || (u == vhi && (unsigned int)m <= vlo)){
            unsigned int slot = atomicAdd(&cnt[wv], 1u);
            if (slot < CAPW)
                cand[wv][slot] = (((unsigned long long)u) << 12) | (unsigned int)m;
        }
    }
    const unsigned int C = cnt[wv];
    if (C <= CAPW){
        for (unsigned int i = lane; i < C; i += 64){
            unsigned long long mk = cand[wv][i];
            unsigned int rank = 0;
            for (unsigned int j = 0; j < C; j++) rank += (cand[wv][j] < mk) ? 1u : 0u;
            if (rank < K_) knn[(size_t)p*K_ + rank] = (int)(mk & 0xFFFull);
        }
    } else {
        unsigned long long last = 0ull;
        for (int it = 0; it < K_; it++){
            unsigned long long cm = ~0ull;
            #pragma unroll 4
            for (int i = 0; i < 64; i++){
                const int m = i*64 + lane;
                f32x4 c = pb[m];
                float d = fmaf(ax, c[0], fmaf(ay, c[1], fmaf(az, c[2], c[3])));
                unsigned long long key = (((unsigned long long)mono(d)) << 12) | (unsigned int)m;
                if (key > last && key < cm) cm = key;
            }
            #pragma unroll
            for (int off = 32; off; off >>= 1){
                unsigned long long o = __shfl_xor(cm, off, 64);
                cm = o < cm ? o : cm;
            }
            if (lane == 0) knn[(size_t)p*K_ + it] = (int)(cm & 0xFFFull);
            last = cm;
        }
    }
}

// ---------------- MFMA GEMM body: 128x64 tile, BK=32, gload_lds double buffer ----
// 4 waves, each owns a 32x64 strip (2x4 fragments). 24KB LDS -> ~6 blocks/CU.
template<int MODE>
__device__ __forceinline__ void gemm_body(
    const unsigned short* __restrict__ X, int ldx,
    const unsigned short* __restrict__ W, int Kin,
    const float* __restrict__ e0, const float* __restrict__ e1, const float* __restrict__ e2,
    unsigned short* __restrict__ Y, int ldy,
    const float* __restrict__ resid, float* __restrict__ out,
    unsigned short (*As)[128*32], unsigned short (*Bs)[64*32], int bx, int by)
{
    const int tid = threadIdx.x, wid = tid >> 6, lane = tid & 63;
    const int lr = lane & 15, lg = lane >> 4;
    const int m0 = bx*128, n0 = by*64;
    const int lrow = lane >> 2, lcol = (lane & 3)*8;   // 16 rows x 32 cols per instr

    const unsigned short* Ag0 = X + (size_t)(m0 + wid*32 + lrow)*ldx + lcol;
    const unsigned short* Ag1 = X + (size_t)(m0 + wid*32 + 16 + lrow)*ldx + lcol;
    const unsigned short* Bg0 = W + (size_t)(n0 + wid*16 + lrow)*Kin + lcol;

    f32x4 acc[2][4] = {};
    const int NT = Kin >> 5;
    int buf = 0;
    gload_lds16(Ag0, &As[0][(wid*32)*32]);
    gload_lds16(Ag1, &As[0][(wid*32+16)*32]);
    gload_lds16(Bg0, &Bs[0][(wid*16)*32]);
    __syncthreads();
    for (int kt = 0; kt < NT; kt++){
        if (kt + 1 < NT){
            const int k = (kt+1)*32;
            gload_lds16(Ag0 + k, &As[buf^1][(wid*32)*32]);
            gload_lds16(Ag1 + k, &As[buf^1][(wid*32+16)*32]);
            gload_lds16(Bg0 + k, &Bs[buf^1][(wid*16)*32]);
        }
        bf16x8 a[2], b[4];
        #pragma unroll
        for (int mi = 0; mi < 2; mi++)
            a[mi] = *(const bf16x8*)&As[buf][(wid*32 + mi*16 + lr)*32 + lg*8];
        #pragma unroll
        for (int ni = 0; ni < 4; ni++)
            b[ni] = *(const bf16x8*)&Bs[buf][(ni*16 + lr)*32 + lg*8];
        #pragma unroll
        for (int mi = 0; mi < 2; mi++){
            #pragma unroll
            for (int ni = 0; ni < 4; ni++)
                acc[mi][ni] = __builtin_amdgcn_mfma_f32_16x16x32_bf16(a[mi], b[ni], acc[mi][ni], 0, 0, 0);
        }
        __syncthreads();
        buf ^= 1;
    }
    #pragma unroll
    for (int mi = 0; mi < 2; mi++){
        const int pbase = m0 + wid*32 + mi*16 + lg*4;
        #pragma unroll
        for (int ni = 0; ni < 4; ni++){
            const int o = n0 + ni*16 + lr;
            if (MODE == 0){
                const float* bp = (o < 256) ? e0 : ((o < 512) ? e1 : e2);
                float bias = bp[o & 255];
                #pragma unroll
                for (int r = 0; r < 4; r++)
                    Y[(size_t)(pbase + r)*ldy + o] = f2bf(acc[mi][ni][r] + bias);
            } else if (MODE == 1){
                float sc = e0[o] * 0.9999950000374997f;
                float sh = e1[o];
                #pragma unroll
                for (int r = 0; r < 4; r++){
                    float vv = fmaf(acc[mi][ni][r], sc, sh);
                    Y[(size_t)(pbase + r)*ldy + o] = f2bf(fmaxf(vv, 0.f));
                }
            } else {
                float bias = e0[o];
                const int b = pbase >> 12, nn = pbase & 4095;
                const size_t adr = ((size_t)b*C_ + o)*N_ + nn;
                f32x4 rv = *(const f32x4*)(resid + adr);
                f32x4 ov;
                #pragma unroll
                for (int r = 0; r < 4; r++) ov[r] = acc[mi][ni][r] + bias + rv[r];
                *(f32x4*)(out + adr) = ov;
            }
        }
    }
}

// merged projection GEMMs: y<8 -> QQ (N=512) ; y>=8 -> KVD (N=768)
__global__ __launch_bounds__(256) void k_proj(
    const unsigned short* __restrict__ F, const unsigned short* __restrict__ XBT,
    const unsigned short* __restrict__ WQcat, const unsigned short* __restrict__ WKVD,
    const float* __restrict__ bq, const float* __restrict__ bqd,
    const float* __restrict__ bk, const float* __restrict__ bv, const float* __restrict__ bkd,
    unsigned short* __restrict__ QQ, unsigned short* __restrict__ KVD)
{
    __shared__ __align__(16) unsigned short As[2][128*32];
    __shared__ __align__(16) unsigned short Bs[2][64*32];
    if (blockIdx.y < 8)
        gemm_body<0>(F, 768, WQcat, 256, bq, bqd, nullptr, QQ, 512, nullptr, nullptr,
                     As, Bs, blockIdx.x, blockIdx.y);
    else
        gemm_body<0>(XBT, 256, WKVD, 256, bk, bv, bkd, KVD, 768, nullptr, nullptr,
                     As, Bs, blockIdx.x, blockIdx.y - 8);
}

template<int MODE>
__global__ __launch_bounds__(256) void k_gemm(
    const unsigned short* __restrict__ X, int ldx,
    const unsigned short* __restrict__ W, int Kin,
    const float* __restrict__ e0, const float* __restrict__ e1, const float* __restrict__ e2,
    unsigned short* __restrict__ Y, int ldy,
    const float* __restrict__ resid, float* __restrict__ out)
{
    __shared__ __align__(16) unsigned short As[2][128*32];
    __shared__ __align__(16) unsigned short Bs[2][64*32];
    gemm_body<MODE>(X, ldx, W, Kin, e0, e1, e2, Y, ldy, resid, out,
                    As, Bs, blockIdx.x, blockIdx.y);
}

// ---------------- dual-path neighbor attention (unchanged from round 10) ----------
__global__ __launch_bounds__(256) void k_attn(
    const unsigned short* __restrict__ QQ, const unsigned short* __restrict__ KVD,
    const int* __restrict__ KNN, const int* __restrict__ order,
    const float* __restrict__ lnsw, const float* __restrict__ lnsb,
    const float* __restrict__ lndw, const float* __restrict__ lndb,
    unsigned short* __restrict__ F)
{
    __shared__ float q_l[2][2][2][128];
    __shared__ float w_l[2][2][2][4][33];
    __shared__ int   idx_l[2][2][32];
    __shared__ float part_l[2][2][4];

    const int tid = threadIdx.x;
    const int wid = tid >> 6, lane = tid & 63;
    const int ps = wid >> 1, wh = wid & 1;
    const int bid = blockIdx.x;
    const int xcd = bid & 7, ib = bid >> 3;
    const int batch = xcd & 1, quarter = xcd >> 1;
    const int jj = quarter*1024 + ib*2 + ps;
    const int p = order[(batch << 12) + jj];
    const int b = batch;

    {
        const unsigned short* qrow = QQ + (size_t)p*512 + wh*128 + lane*2;
        unsigned int us = *(const unsigned int*)qrow;
        unsigned int ud = *(const unsigned int*)(qrow + 256);
        q_l[ps][wh][0][lane*2]   = bf2f((unsigned short)(us & 0xffff));
        q_l[ps][wh][0][lane*2+1] = bf2f((unsigned short)(us >> 16));
        q_l[ps][wh][1][lane*2]   = bf2f((unsigned short)(ud & 0xffff));
        q_l[ps][wh][1][lane*2+1] = bf2f((unsigned short)(ud >> 16));
        if (lane < 32) idx_l[ps][wh][lane] = KNN[(size_t)p*K_ + lane];
    }

    const int hh = lane >> 5, kk = lane & 31;
    const int tq = lane >> 4, c = lane & 15;
    const int hl = c >> 2;

    const int nbr_qk = idx_l[ps][wh][kk];
    int nbt[8];
    #pragma unroll
    for (int i = 0; i < 8; i++) nbt[i] = idx_l[ps][wh][tq + i*4];

    const unsigned short* rowb = KVD + (size_t)((b<<12) + nbr_qk)*768;
    bf16x8 kx[2][4], dx[2][4];
    #pragma unroll
    for (int j = 0; j < 2; j++){
        const int h = wh*4 + j*2 + hh;
        const bf16x8* kr = (const bf16x8*)(rowb + h*32);
        const bf16x8* dr = (const bf16x8*)(rowb + 512 + h*32);
        #pragma unroll
        for (int cc = 0; cc < 4; cc++){ kx[j][cc] = kr[cc]; dx[j][cc] = dr[cc]; }
    }
    const unsigned short* vbase = KVD + 256 + wh*128 + c*8;
    bf16x8 vx[8];
    #pragma unroll
    for (int i = 0; i < 8; i++)
        vx[i] = *(const bf16x8*)(vbase + (size_t)((b<<12) + nbt[i])*768);

    #pragma unroll
    for (int j = 0; j < 2; j++){
        const int hloc = j*2 + hh;
        const float* qs = &q_l[ps][wh][0][hloc*32];
        const float* qd = &q_l[ps][wh][1][hloc*32];
        float s = 0.f, dd = 0.f;
        #pragma unroll
        for (int cc = 0; cc < 4; cc++){
            #pragma unroll
            for (int e = 0; e < 8; e++){
                const int d = cc*8 + e;
                s = fmaf(qs[d], bf2f((unsigned short)kx[j][cc][e]), s);
                float df = qd[d] - bf2f((unsigned short)dx[j][cc][e]);
                dd = fmaf(df, df, dd);
            }
        }
        float sim = s * 0.17677669529663687f;   // 1/sqrt(32)
        float dist = sqrtf(dd);
        float m1 = sim, m2 = dist;
        #pragma unroll
        for (int off = 1; off < 32; off <<= 1){
            m1 = fmaxf(m1, __shfl_xor(m1, off, 64));
            m2 = fmaxf(m2, __shfl_xor(m2, off, 64));
        }
        float e1v = __expf(sim - m1);
        float e2v = __expf(dist - m2);
        float s1 = e1v, s2 = e2v;
        #pragma unroll
        for (int off = 1; off < 32; off <<= 1){
            s1 += __shfl_xor(s1, off, 64);
            s2 += __shfl_xor(s2, off, 64);
        }
        w_l[ps][wh][0][hloc][kk] = e1v / s1;
        w_l[ps][wh][1][hloc][kk] = e2v / s2;
    }

    float cs[8] = {0,0,0,0,0,0,0,0}, cd[8] = {0,0,0,0,0,0,0,0};
    #pragma unroll
    for (int i = 0; i < 8; i++){
        const int t = tq + i*4;
        const float wsv = w_l[ps][wh][0][hl][t];
        const float wdv = w_l[ps][wh][1][hl][t];
        #pragma unroll
        for (int e = 0; e < 8; e++){
            float vf = bf2f((unsigned short)vx[i][e]);
            cs[e] = fmaf(wsv, vf, cs[e]);
            cd[e] = fmaf(wdv, vf, cd[e]);
        }
    }
    #pragma unroll
    for (int e = 0; e < 8; e++){
        cs[e] += __shfl_xor(cs[e], 16, 64); cs[e] += __shfl_xor(cs[e], 32, 64);
        cd[e] += __shfl_xor(cd[e], 16, 64); cd[e] += __shfl_xor(cd[e], 32, 64);
    }
    float s1 = 0.f, q1 = 0.f, s2 = 0.f, q2 = 0.f;
    #pragma unroll
    for (int e = 0; e < 8; e++){
        s1 += cs[e]; q1 = fmaf(cs[e], cs[e], q1);
        s2 += cd[e]; q2 = fmaf(cd[e], cd[e], q2);
    }
    #pragma unroll
    for (int off = 1; off < 16; off <<= 1){
        s1 += __shfl_xor(s1, off, 64); q1 += __shfl_xor(q1, off, 64);
        s2 += __shfl_xor(s2, off, 64); q2 += __shfl_xor(q2, off, 64);
    }
    if (lane == 0){
        part_l[ps][wh][0] = s1; part_l[ps][wh][1] = q1;
        part_l[ps][wh][2] = s2; part_l[ps][wh][3] = q2;
    }
    __syncthreads();
    const float S1 = s1 + part_l[ps][wh^1][0];
    const float Q1 = q1 + part_l[ps][wh^1][1];
    const float S2 = s2 + part_l[ps][wh^1][2];
    const float Q2 = q2 + part_l[ps][wh^1][3];
    const float m1 = S1*(1.f/256.f), m2 = S2*(1.f/256.f);
    const float r1 = rsqrtf(Q1*(1.f/256.f) - m1*m1 + 1e-5f);
    const float r2 = rsqrtf(Q2*(1.f/256.f) - m2*m2 + 1e-5f);

    if (tq == 0){
        bf16x8 ob;
        #pragma unroll
        for (int e = 0; e < 8; e++){
            const int cg = wh*128 + c*8 + e;
            ob[e] = (short)f2bf((cs[e]-m1)*r1*lnsw[cg] + lnsb[cg]);
        }
        *(bf16x8*)(F + (size_t)p*768 + 256 + wh*128 + c*8) = ob;
    } else if (tq == 1){
        bf16x8 ob;
        #pragma unroll
        for (int e = 0; e < 8; e++){
            const int cg = wh*128 + c*8 + e;
            ob[e] = (short)f2bf((cd[e]-m2)*r2*lndw[cg] + lndb[cg]);
        }
        *(bf16x8*)(F + (size_t)p*768 + 512 + wh*128 + c*8) = ob;
    }
}

extern "C" void kernel_launch(void* const* d_in, const int* in_sizes, int n_in,
                              void* d_out, int out_size, void* d_ws, size_t ws_size,
                              hipStream_t stream)
{
    const float* xyzA   = (const float*)d_in[0];
    const float* xyzB   = (const float*)d_in[1];
    const float* featA  = (const float*)d_in[2];
    const float* featB  = (const float*)d_in[3];
    const float* ln_in_w= (const float*)d_in[4];
    const float* ln_in_b= (const float*)d_in[5];
    const float* wq  = (const float*)d_in[6];
    const float* bq  = (const float*)d_in[7];
    const float* wk  = (const float*)d_in[8];
    const float* bk  = (const float*)d_in[9];
    const float* wv  = (const float*)d_in[10];
    const float* bv  = (const float*)d_in[11];
    const float* wqd = (const float*)d_in[12];
    const float* bqd = (const float*)d_in[13];
    const float* wkd = (const float*)d_in[14];
    const float* bkd = (const float*)d_in[15];
    const float* lnsw = (const float*)d_in[16];
    const float* lnsb = (const float*)d_in[17];
    const float* lndw = (const float*)d_in[18];
    const float* lndb = (const float*)d_in[19];
    const float* fw1 = (const float*)d_in[20];
    const float* bng = (const float*)d_in[21];
    const float* bnb = (const float*)d_in[22];
    const float* fw2 = (const float*)d_in[23];
    const float* fb2 = (const float*)d_in[24];
    float* out = (float*)d_out;
    char* ws = (char*)d_ws;

    unsigned short* F    = (unsigned short*)(ws + 0);          // 8192*768 bf16
    unsigned short* XBT  = (unsigned short*)(ws + 12582912);   // 8192*256
    unsigned short* QQ   = (unsigned short*)(ws + 16777216);   // 8192*512
    unsigned short* KVD  = (unsigned short*)(ws + 25165824);   // 8192*768
    unsigned short* Y1   = (unsigned short*)(ws + 37748736);   // 8192*512 ; PB earlier
    f32x4*          PB   = (f32x4*)(ws + 37748736);            // dead before fus1
    int*            KNNi = (int*)(ws + 46137344);              // 8192*32
    int*            ORD  = (int*)(ws + 47185920);              // 8192*4
    unsigned short* Wb   = (unsigned short*)(ws + 47251456);   // 851968 bf16
    unsigned short* WQcat = Wb;                // 512x256
    unsigned short* WKVD  = Wb + 131072;       // 768x256
    unsigned short* W1b   = Wb + 327680;       // 512x768
    unsigned short* W2b   = Wb + 720896;       // 256x512

    k_pre<<<4130, 256, 0, stream>>>(wq, wqd, wk, wv, wkd, fw1, fw2, Wb,
                                    xyzB, PB, xyzA, ORD,
                                    featA, ln_in_w, ln_in_b, F, featB, XBT);
    k_knn<<<2048, 256, 0, stream>>>(xyzA, PB, KNNi);

    k_proj<<<dim3(64,20), 256, 0, stream>>>(F, XBT, WQcat, WKVD, bq, bqd, bk, bv, bkd, QQ, KVD);

    k_attn<<<4096, 256, 0, stream>>>(QQ, KVD, KNNi, ORD, lnsw, lnsb, lndw, lndb, F);

    k_gemm<1><<<dim3(64,8), 256, 0, stream>>>(F,  768, W1b, 768, bng, bnb, nullptr, Y1, 512, nullptr, nullptr);
    k_gemm<2><<<dim3(64,4), 256, 0, stream>>>(Y1, 512, W2b, 512, fb2, nullptr, nullptr, nullptr, 0, featA, out);
}